// Round 1
// baseline (1326.088 us; speedup 1.0000x reference)
//
#include <hip/hip_runtime.h>
#include <hip/hip_bf16.h>

__device__ __forceinline__ float wave_reduce_sum(float v) {
#pragma unroll
    for (int m = 32; m > 0; m >>= 1) v += __shfl_xor(v, m, 64);
    return v;
}
__device__ __forceinline__ float wave_reduce_max(float v) {
#pragma unroll
    for (int m = 32; m > 0; m >>= 1) v = fmaxf(v, __shfl_xor(v, m, 64));
    return v;
}

// ---------------- CSR build (by dst) ----------------
__global__ void k_hist(const int* __restrict__ dst, int* __restrict__ deg, int e) {
    int i = blockIdx.x * blockDim.x + threadIdx.x;
    if (i < e) atomicAdd(&deg[dst[i]], 1);
}

// exclusive scan of deg[0..n) -> rowst[0..n], single block of 1024
__global__ void k_scan(const int* __restrict__ deg, int* __restrict__ rowst, int n) {
    __shared__ int buf[1024];
    __shared__ int carry;
    int tid = threadIdx.x;
    if (tid == 0) carry = 0;
    __syncthreads();
    for (int base = 0; base < n; base += 1024) {
        int x = (base + tid < n) ? deg[base + tid] : 0;
        buf[tid] = x;
        __syncthreads();
        for (int off = 1; off < 1024; off <<= 1) {
            int t = (tid >= off) ? buf[tid - off] : 0;
            __syncthreads();
            buf[tid] += t;
            __syncthreads();
        }
        int incl = buf[tid];
        int c = carry;
        __syncthreads();
        if (base + tid < n) rowst[base + tid] = c + incl - x;
        if (tid == 1023) carry = c + incl;
        __syncthreads();
    }
    if (tid == 0) rowst[n] = carry;
}

__global__ void k_copy(const int* __restrict__ a, int* __restrict__ b, int n) {
    int i = blockIdx.x * blockDim.x + threadIdx.x;
    if (i < n) b[i] = a[i];
}

__global__ void k_fill(const int* __restrict__ src, const int* __restrict__ dst,
                       int* __restrict__ cursor, int* __restrict__ csrc, int e) {
    int i = blockIdx.x * blockDim.x + threadIdx.x;
    if (i < e) {
        int p = atomicAdd(&cursor[dst[i]], 1);
        csrc[p] = src[i];
    }
}

// ---------------- Linear + L2-norm prep ----------------
// h = X @ W^T + b ; rinv = 1/max(||h||,eps) ; exself = exp((||h||*rinv)^2)
// Optional ReLU applied to input X on read (folds previous layer's ReLU).
template <int DOUT, bool RELU>
__global__ __launch_bounds__(256) void k_linear(
    const float* __restrict__ X, const float* __restrict__ W, const float* __restrict__ B,
    float* __restrict__ H, float* __restrict__ rinv, float* __restrict__ exself, int n)
{
    __shared__ float sW[DOUT * 128];   // float4 quads XOR-swizzled by row
    __shared__ float sX[16 * 128];
    const int tid = threadIdx.x, wave = tid >> 6, lane = tid & 63;

    // stage W (row c, quad q stored at quad index q ^ (c & 7))
    for (int i = tid; i < DOUT * 32; i += 256) {
        int c = i >> 5, q = i & 31;
        float4 v = reinterpret_cast<const float4*>(W)[i];
        int qs = q ^ (c & 7);
        *reinterpret_cast<float4*>(&sW[c * 128 + qs * 4]) = v;
    }

    const int c0 = lane;
    const float b0 = B[c0];
    float b1 = 0.0f;
    if (DOUT == 128) b1 = B[c0 + 64];

    for (int rg = blockIdx.x * 16; rg < n; rg += gridDim.x * 16) {
        __syncthreads();
        // stage 16 input rows
        for (int i = tid; i < 16 * 32; i += 256) {
            int r = i >> 5, q = i & 31;
            int row = rg + r;
            float4 v = make_float4(0.f, 0.f, 0.f, 0.f);
            if (row < n) v = reinterpret_cast<const float4*>(X + (size_t)row * 128)[q];
            if (RELU) {
                v.x = fmaxf(v.x, 0.f); v.y = fmaxf(v.y, 0.f);
                v.z = fmaxf(v.z, 0.f); v.w = fmaxf(v.w, 0.f);
            }
            *reinterpret_cast<float4*>(&sX[r * 128 + q * 4]) = v;
        }
        __syncthreads();

        float acc0[4] = {0.f, 0.f, 0.f, 0.f};
        float acc1[4] = {0.f, 0.f, 0.f, 0.f};
#pragma unroll
        for (int q = 0; q < 32; q++) {
            int qs = q ^ (c0 & 7);
            float4 w0 = *reinterpret_cast<const float4*>(&sW[c0 * 128 + qs * 4]);
            float4 w1 = w0;
            if (DOUT == 128)
                w1 = *reinterpret_cast<const float4*>(&sW[(c0 + 64) * 128 + qs * 4]);
#pragma unroll
            for (int r = 0; r < 4; r++) {
                float4 xv = *reinterpret_cast<const float4*>(&sX[(wave * 4 + r) * 128 + q * 4]);
                acc0[r] += xv.x * w0.x + xv.y * w0.y + xv.z * w0.z + xv.w * w0.w;
                if (DOUT == 128)
                    acc1[r] += xv.x * w1.x + xv.y * w1.y + xv.z * w1.z + xv.w * w1.w;
            }
        }
#pragma unroll
        for (int r = 0; r < 4; r++) {
            int row = rg + wave * 4 + r;
            float v0 = acc0[r] + b0;
            float v1 = acc1[r] + b1;
            float ss = v0 * v0;
            if (DOUT == 128) ss += v1 * v1;
            float tot = wave_reduce_sum(ss);
            if (row < n) {
                H[(size_t)row * DOUT + c0] = v0;
                if (DOUT == 128) H[(size_t)row * DOUT + c0 + 64] = v1;
                if (lane == 0) {
                    float nrm = sqrtf(tot);
                    float ri = 1.0f / fmaxf(nrm, 1e-12f);
                    float s = nrm * ri;
                    rinv[row] = ri;
                    exself[row] = expf(s * s);
                }
            }
        }
    }
}

// ---------------- Fused attention aggregation (one wave per node) ----------------
// out[i] = (exself*h[i] + sum_e exp(cos(i,src_e)) * h[src_e]) / (exself + sum_e exp(...))
__global__ __launch_bounds__(256) void k_agg128(
    const float* __restrict__ H, const float* __restrict__ rinv, const float* __restrict__ exself,
    const int* __restrict__ rowst, const int* __restrict__ csrc,
    float* __restrict__ OUT, int n)
{
    int wave = threadIdx.x >> 6, lane = threadIdx.x & 63;
    int node = blockIdx.x * 4 + wave;
    if (node >= n) return;
    float2 hi = *reinterpret_cast<const float2*>(&H[(size_t)node * 128 + lane * 2]);
    float ri = rinv[node];
    float es = exself[node];
    float denom = es;
    float2 acc = make_float2(es * hi.x, es * hi.y);
    int p0 = rowst[node], p1 = rowst[node + 1];
    for (int p = p0; p < p1; p++) {
        int s = csrc[p];
        float2 hs = *reinterpret_cast<const float2*>(&H[(size_t)s * 128 + lane * 2]);
        float d = wave_reduce_sum(hs.x * hi.x + hs.y * hi.y);
        float ex = expf(d * ri * rinv[s]);
        denom += ex;
        acc.x += ex * hs.x;
        acc.y += ex * hs.y;
    }
    float inv = 1.0f / denom;
    float2 o = make_float2(acc.x * inv, acc.y * inv);
    *reinterpret_cast<float2*>(&OUT[(size_t)node * 128 + lane * 2]) = o;
}

// D=64 variant with fused log_softmax epilogue (64 lanes = 64 classes)
__global__ __launch_bounds__(256) void k_agg64_lsm(
    const float* __restrict__ H, const float* __restrict__ rinv, const float* __restrict__ exself,
    const int* __restrict__ rowst, const int* __restrict__ csrc,
    float* __restrict__ OUT, int n)
{
    int wave = threadIdx.x >> 6, lane = threadIdx.x & 63;
    int node = blockIdx.x * 4 + wave;
    if (node >= n) return;
    float hi = H[(size_t)node * 64 + lane];
    float ri = rinv[node];
    float es = exself[node];
    float denom = es;
    float acc = es * hi;
    int p0 = rowst[node], p1 = rowst[node + 1];
    for (int p = p0; p < p1; p++) {
        int s = csrc[p];
        float hs = H[(size_t)s * 64 + lane];
        float d = wave_reduce_sum(hs * hi);
        float ex = expf(d * ri * rinv[s]);
        denom += ex;
        acc += ex * hs;
    }
    float val = acc / denom;
    float m = wave_reduce_max(val);
    float se = wave_reduce_sum(expf(val - m));
    OUT[(size_t)node * 64 + lane] = val - m - logf(se);
}

extern "C" void kernel_launch(void* const* d_in, const int* in_sizes, int n_in,
                              void* d_out, int out_size, void* d_ws, size_t ws_size,
                              hipStream_t stream)
{
    const float* x  = (const float*)d_in[0];
    const int*   ei = (const int*)d_in[1];
    const float* W1 = (const float*)d_in[2];
    const float* b1 = (const float*)d_in[3];
    const float* W2 = (const float*)d_in[4];
    const float* b2 = (const float*)d_in[5];
    const float* W3 = (const float*)d_in[6];
    const float* b3 = (const float*)d_in[7];
    float* out = (float*)d_out;

    const int n = in_sizes[0] / 128;
    const int e = in_sizes[1] / 2;
    const int* esrc = ei;
    const int* edst = ei + e;

    char* w = (char*)d_ws;
    float* h    = (float*)w;  w += (size_t)n * 128 * sizeof(float);
    float* conv = (float*)w;  w += (size_t)n * 128 * sizeof(float);
    float* rinv = (float*)w;  w += (size_t)n * sizeof(float);
    float* exs  = (float*)w;  w += (size_t)n * sizeof(float);
    int* rowst  = (int*)w;    w += (size_t)(n + 1) * sizeof(int);
    int* cursor = (int*)w;    w += (size_t)n * sizeof(int);
    int* csrc   = (int*)w;    w += (size_t)e * sizeof(int);

    // ---- CSR build (shared by all 3 layers) ----
    hipMemsetAsync(cursor, 0, (size_t)n * sizeof(int), stream);
    k_hist<<<(e + 255) / 256, 256, 0, stream>>>(edst, cursor, e);
    k_scan<<<1, 1024, 0, stream>>>(cursor, rowst, n);
    k_copy<<<(n + 255) / 256, 256, 0, stream>>>(rowst, cursor, n);
    k_fill<<<(e + 255) / 256, 256, 0, stream>>>(esrc, edst, cursor, csrc, e);

    const int lgrid = (n + 15) / 16;
    const int agrid = (n + 3) / 4;

    // layer 1
    k_linear<128, false><<<lgrid, 256, 0, stream>>>(x, W1, b1, h, rinv, exs, n);
    k_agg128<<<agrid, 256, 0, stream>>>(h, rinv, exs, rowst, csrc, conv, n);
    // layer 2 (ReLU folded into input read)
    k_linear<128, true><<<lgrid, 256, 0, stream>>>(conv, W2, b2, h, rinv, exs, n);
    k_agg128<<<agrid, 256, 0, stream>>>(h, rinv, exs, rowst, csrc, conv, n);
    // layer 3 + log_softmax
    k_linear<64, true><<<lgrid, 256, 0, stream>>>(conv, W3, b3, h, rinv, exs, n);
    k_agg64_lsm<<<agrid, 256, 0, stream>>>(h, rinv, exs, rowst, csrc, out, n);
}

// Round 2
// 682.464 us; speedup vs baseline: 1.9431x; 1.9431x over previous
//
#include <hip/hip_runtime.h>
#include <hip/hip_bf16.h>

__device__ __forceinline__ float wave_reduce_sum(float v) {
#pragma unroll
    for (int m = 32; m > 0; m >>= 1) v += __shfl_xor(v, m, 64);
    return v;
}
__device__ __forceinline__ float wave_reduce_max(float v) {
#pragma unroll
    for (int m = 32; m > 0; m >>= 1) v = fmaxf(v, __shfl_xor(v, m, 64));
    return v;
}

// ---------------- CSR build (by dst) ----------------
__global__ void k_hist(const int* __restrict__ dst, int* __restrict__ deg, int e) {
    int i = blockIdx.x * blockDim.x + threadIdx.x;
    if (i < e) atomicAdd(&deg[dst[i]], 1);
}

// exclusive scan of deg[0..n) -> rowst[0..n], single block of 1024
__global__ void k_scan(const int* __restrict__ deg, int* __restrict__ rowst, int n) {
    __shared__ int buf[1024];
    __shared__ int carry;
    int tid = threadIdx.x;
    if (tid == 0) carry = 0;
    __syncthreads();
    for (int base = 0; base < n; base += 1024) {
        int x = (base + tid < n) ? deg[base + tid] : 0;
        buf[tid] = x;
        __syncthreads();
        for (int off = 1; off < 1024; off <<= 1) {
            int t = (tid >= off) ? buf[tid - off] : 0;
            __syncthreads();
            buf[tid] += t;
            __syncthreads();
        }
        int incl = buf[tid];
        int c = carry;
        __syncthreads();
        if (base + tid < n) rowst[base + tid] = c + incl - x;
        if (tid == 1023) carry = c + incl;
        __syncthreads();
    }
    if (tid == 0) rowst[n] = carry;
}

__global__ void k_copy(const int* __restrict__ a, int* __restrict__ b, int n) {
    int i = blockIdx.x * blockDim.x + threadIdx.x;
    if (i < n) b[i] = a[i];
}

__global__ void k_fill(const int* __restrict__ src, const int* __restrict__ dst,
                       int* __restrict__ cursor, int* __restrict__ csrc, int e) {
    int i = blockIdx.x * blockDim.x + threadIdx.x;
    if (i < e) {
        int p = atomicAdd(&cursor[dst[i]], 1);
        csrc[p] = src[i];
    }
}

// ---------------- Linear + L2-norm prep ----------------
// h = X @ W^T + b ; rinv = 1/max(||h||,eps) ; exself = exp((||h||*rinv)^2)
// Optional ReLU applied to input X on read (folds previous layer's ReLU).
template <int DOUT, bool RELU>
__global__ __launch_bounds__(256) void k_linear(
    const float* __restrict__ X, const float* __restrict__ W, const float* __restrict__ B,
    float* __restrict__ H, float* __restrict__ rinv, float* __restrict__ exself, int n)
{
    __shared__ float sW[DOUT * 128];   // float4 quads XOR-swizzled by row
    __shared__ float sX[16 * 128];
    const int tid = threadIdx.x, wave = tid >> 6, lane = tid & 63;

    // stage W (row c, quad q stored at quad index q ^ (c & 7))
    for (int i = tid; i < DOUT * 32; i += 256) {
        int c = i >> 5, q = i & 31;
        float4 v = reinterpret_cast<const float4*>(W)[i];
        int qs = q ^ (c & 7);
        *reinterpret_cast<float4*>(&sW[c * 128 + qs * 4]) = v;
    }

    const int c0 = lane;
    const float b0 = B[c0];
    float b1 = 0.0f;
    if (DOUT == 128) b1 = B[c0 + 64];

    for (int rg = blockIdx.x * 16; rg < n; rg += gridDim.x * 16) {
        __syncthreads();
        // stage 16 input rows
        for (int i = tid; i < 16 * 32; i += 256) {
            int r = i >> 5, q = i & 31;
            int row = rg + r;
            float4 v = make_float4(0.f, 0.f, 0.f, 0.f);
            if (row < n) v = reinterpret_cast<const float4*>(X + (size_t)row * 128)[q];
            if (RELU) {
                v.x = fmaxf(v.x, 0.f); v.y = fmaxf(v.y, 0.f);
                v.z = fmaxf(v.z, 0.f); v.w = fmaxf(v.w, 0.f);
            }
            *reinterpret_cast<float4*>(&sX[r * 128 + q * 4]) = v;
        }
        __syncthreads();

        float acc0[4] = {0.f, 0.f, 0.f, 0.f};
        float acc1[4] = {0.f, 0.f, 0.f, 0.f};
        // unroll 4 (NOT full): full unroll spilled to scratch (VGPR=256,
        // 864 MB HBM scratch traffic, 400us). 4x keeps live set ~120 VGPR.
#pragma unroll 4
        for (int q = 0; q < 32; q++) {
            int qs = q ^ (c0 & 7);
            float4 w0 = *reinterpret_cast<const float4*>(&sW[c0 * 128 + qs * 4]);
            float4 w1 = w0;
            if (DOUT == 128)
                w1 = *reinterpret_cast<const float4*>(&sW[(c0 + 64) * 128 + qs * 4]);
#pragma unroll
            for (int r = 0; r < 4; r++) {
                float4 xv = *reinterpret_cast<const float4*>(&sX[(wave * 4 + r) * 128 + q * 4]);
                acc0[r] += xv.x * w0.x + xv.y * w0.y + xv.z * w0.z + xv.w * w0.w;
                if (DOUT == 128)
                    acc1[r] += xv.x * w1.x + xv.y * w1.y + xv.z * w1.z + xv.w * w1.w;
            }
        }
#pragma unroll
        for (int r = 0; r < 4; r++) {
            int row = rg + wave * 4 + r;
            float v0 = acc0[r] + b0;
            float v1 = acc1[r] + b1;
            float ss = v0 * v0;
            if (DOUT == 128) ss += v1 * v1;
            float tot = wave_reduce_sum(ss);
            if (row < n) {
                H[(size_t)row * DOUT + c0] = v0;
                if (DOUT == 128) H[(size_t)row * DOUT + c0 + 64] = v1;
                if (lane == 0) {
                    float nrm = sqrtf(tot);
                    float ri = 1.0f / fmaxf(nrm, 1e-12f);
                    float s = nrm * ri;
                    rinv[row] = ri;
                    exself[row] = expf(s * s);
                }
            }
        }
    }
}

// ---------------- Fused attention aggregation (one wave per node) ----------------
// out[i] = (exself*h[i] + sum_e exp(cos(i,src_e)) * h[src_e]) / (exself + sum_e exp(...))
__global__ __launch_bounds__(256) void k_agg128(
    const float* __restrict__ H, const float* __restrict__ rinv, const float* __restrict__ exself,
    const int* __restrict__ rowst, const int* __restrict__ csrc,
    float* __restrict__ OUT, int n)
{
    int wave = threadIdx.x >> 6, lane = threadIdx.x & 63;
    int node = blockIdx.x * 4 + wave;
    if (node >= n) return;
    float2 hi = *reinterpret_cast<const float2*>(&H[(size_t)node * 128 + lane * 2]);
    float ri = rinv[node];
    float es = exself[node];
    float denom = es;
    float2 acc = make_float2(es * hi.x, es * hi.y);
    int p0 = rowst[node], p1 = rowst[node + 1];
    for (int p = p0; p < p1; p++) {
        int s = csrc[p];
        float2 hs = *reinterpret_cast<const float2*>(&H[(size_t)s * 128 + lane * 2]);
        float d = wave_reduce_sum(hs.x * hi.x + hs.y * hi.y);
        float ex = expf(d * ri * rinv[s]);
        denom += ex;
        acc.x += ex * hs.x;
        acc.y += ex * hs.y;
    }
    float inv = 1.0f / denom;
    float2 o = make_float2(acc.x * inv, acc.y * inv);
    *reinterpret_cast<float2*>(&OUT[(size_t)node * 128 + lane * 2]) = o;
}

// D=64 variant with fused log_softmax epilogue (64 lanes = 64 classes)
__global__ __launch_bounds__(256) void k_agg64_lsm(
    const float* __restrict__ H, const float* __restrict__ rinv, const float* __restrict__ exself,
    const int* __restrict__ rowst, const int* __restrict__ csrc,
    float* __restrict__ OUT, int n)
{
    int wave = threadIdx.x >> 6, lane = threadIdx.x & 63;
    int node = blockIdx.x * 4 + wave;
    if (node >= n) return;
    float hi = H[(size_t)node * 64 + lane];
    float ri = rinv[node];
    float es = exself[node];
    float denom = es;
    float acc = es * hi;
    int p0 = rowst[node], p1 = rowst[node + 1];
    for (int p = p0; p < p1; p++) {
        int s = csrc[p];
        float hs = H[(size_t)s * 64 + lane];
        float d = wave_reduce_sum(hs * hi);
        float ex = expf(d * ri * rinv[s]);
        denom += ex;
        acc += ex * hs;
    }
    float val = acc / denom;
    float m = wave_reduce_max(val);
    float se = wave_reduce_sum(expf(val - m));
    OUT[(size_t)node * 64 + lane] = val - m - logf(se);
}

extern "C" void kernel_launch(void* const* d_in, const int* in_sizes, int n_in,
                              void* d_out, int out_size, void* d_ws, size_t ws_size,
                              hipStream_t stream)
{
    const float* x  = (const float*)d_in[0];
    const int*   ei = (const int*)d_in[1];
    const float* W1 = (const float*)d_in[2];
    const float* b1 = (const float*)d_in[3];
    const float* W2 = (const float*)d_in[4];
    const float* b2 = (const float*)d_in[5];
    const float* W3 = (const float*)d_in[6];
    const float* b3 = (const float*)d_in[7];
    float* out = (float*)d_out;

    const int n = in_sizes[0] / 128;
    const int e = in_sizes[1] / 2;
    const int* esrc = ei;
    const int* edst = ei + e;

    char* w = (char*)d_ws;
    float* h    = (float*)w;  w += (size_t)n * 128 * sizeof(float);
    float* conv = (float*)w;  w += (size_t)n * 128 * sizeof(float);
    float* rinv = (float*)w;  w += (size_t)n * sizeof(float);
    float* exs  = (float*)w;  w += (size_t)n * sizeof(float);
    int* rowst  = (int*)w;    w += (size_t)(n + 1) * sizeof(int);
    int* cursor = (int*)w;    w += (size_t)n * sizeof(int);
    int* csrc   = (int*)w;    w += (size_t)e * sizeof(int);

    // ---- CSR build (shared by all 3 layers) ----
    hipMemsetAsync(cursor, 0, (size_t)n * sizeof(int), stream);
    k_hist<<<(e + 255) / 256, 256, 0, stream>>>(edst, cursor, e);
    k_scan<<<1, 1024, 0, stream>>>(cursor, rowst, n);
    k_copy<<<(n + 255) / 256, 256, 0, stream>>>(rowst, cursor, n);
    k_fill<<<(e + 255) / 256, 256, 0, stream>>>(esrc, edst, cursor, csrc, e);

    const int lgrid = (n + 15) / 16;
    const int agrid = (n + 3) / 4;

    // layer 1
    k_linear<128, false><<<lgrid, 256, 0, stream>>>(x, W1, b1, h, rinv, exs, n);
    k_agg128<<<agrid, 256, 0, stream>>>(h, rinv, exs, rowst, csrc, conv, n);
    // layer 2 (ReLU folded into input read)
    k_linear<128, true><<<lgrid, 256, 0, stream>>>(conv, W2, b2, h, rinv, exs, n);
    k_agg128<<<agrid, 256, 0, stream>>>(h, rinv, exs, rowst, csrc, conv, n);
    // layer 3 + log_softmax
    k_linear<64, true><<<lgrid, 256, 0, stream>>>(conv, W3, b3, h, rinv, exs, n);
    k_agg64_lsm<<<agrid, 256, 0, stream>>>(h, rinv, exs, rowst, csrc, out, n);
}

// Round 3
// 459.439 us; speedup vs baseline: 2.8863x; 1.4854x over previous
//
#include <hip/hip_runtime.h>
#include <hip/hip_bf16.h>

__device__ __forceinline__ float wave_reduce_sum(float v) {
#pragma unroll
    for (int m = 32; m > 0; m >>= 1) v += __shfl_xor(v, m, 64);
    return v;
}
__device__ __forceinline__ float wave_reduce_max(float v) {
#pragma unroll
    for (int m = 32; m > 0; m >>= 1) v = fmaxf(v, __shfl_xor(v, m, 64));
    return v;
}

// ---------------- CSR build (by dst) ----------------
__global__ void k_hist(const int* __restrict__ dst, int* __restrict__ deg, int e) {
    int i = blockIdx.x * blockDim.x + threadIdx.x;
    if (i < e) atomicAdd(&deg[dst[i]], 1);
}

// per-block (1024 elems) inclusive scan via wave shuffles
__global__ __launch_bounds__(1024) void k_scan_blk(
    const int* __restrict__ deg, int* __restrict__ incl, int* __restrict__ bsum, int n)
{
    int tid = threadIdx.x, lane = tid & 63, wv = tid >> 6;
    int gid = blockIdx.x * 1024 + tid;
    int x = (gid < n) ? deg[gid] : 0;
    int v = x;
#pragma unroll
    for (int off = 1; off < 64; off <<= 1) {
        int t = __shfl_up(v, off, 64);
        if (lane >= off) v += t;
    }
    __shared__ int wsum[16];
    if (lane == 63) wsum[wv] = v;
    __syncthreads();
    if (wv == 0) {
        int w = (lane < 16) ? wsum[lane] : 0;
#pragma unroll
        for (int off = 1; off < 16; off <<= 1) {
            int t = __shfl_up(w, off, 64);
            if (lane >= off) w += t;
        }
        if (lane < 16) wsum[lane] = w;
    }
    __syncthreads();
    if (wv > 0) v += wsum[wv - 1];
    if (gid < n) incl[gid] = v;
    if (tid == 1023) bsum[blockIdx.x] = v;   // block total (padding adds 0)
}

// inclusive scan of bsum[0..nb), nb <= 64, one wave, in place
__global__ void k_scan_top(int* __restrict__ bsum, int nb) {
    int lane = threadIdx.x;
    int v = (lane < nb) ? bsum[lane] : 0;
#pragma unroll
    for (int off = 1; off < 64; off <<= 1) {
        int t = __shfl_up(v, off, 64);
        if (lane >= off) v += t;
    }
    if (lane < nb) bsum[lane] = v;
}

// rowst[i] = exclusive scan; also init cursor; rowst[n] = total
__global__ __launch_bounds__(1024) void k_scan_fin(
    const int* __restrict__ deg, const int* __restrict__ incl, const int* __restrict__ bsum,
    int* __restrict__ rowst, int* __restrict__ cursor, int n)
{
    int gid = blockIdx.x * 1024 + threadIdx.x;
    int boff = (blockIdx.x > 0) ? bsum[blockIdx.x - 1] : 0;
    if (gid < n) {
        int r = boff + incl[gid] - deg[gid];
        rowst[gid] = r;
        cursor[gid] = r;
        if (gid == n - 1) rowst[n] = boff + incl[gid];
    }
}

__global__ void k_fill(const int* __restrict__ src, const int* __restrict__ dst,
                       int* __restrict__ cursor, int* __restrict__ csrc, int e) {
    int i = blockIdx.x * blockDim.x + threadIdx.x;
    if (i < e) {
        int p = atomicAdd(&cursor[dst[i]], 1);
        csrc[p] = src[i];
    }
}

// ---------------- Linear + L2-norm prep ----------------
// h = X @ W^T + b ; rinv = 1/max(||h||,eps) ; exself = exp((||h||*rinv)^2)
template <int DOUT, bool RELU>
__global__ __launch_bounds__(256) void k_linear(
    const float* __restrict__ X, const float* __restrict__ W, const float* __restrict__ B,
    float* __restrict__ H, float* __restrict__ rinv, float* __restrict__ exself, int n)
{
    __shared__ float sW[DOUT * 128];   // quad rotation: row c quad q stored at (q+c)&31
    __shared__ float sX[16 * 128];
    const int tid = threadIdx.x, wave = tid >> 6, lane = tid & 63;

    for (int i = tid; i < DOUT * 32; i += 256) {
        int c = i >> 5, q = i & 31;
        float4 v = reinterpret_cast<const float4*>(W)[i];
        int qs = (q + c) & 31;                       // rotation: 32 distinct quads
        *reinterpret_cast<float4*>(&sW[c * 128 + qs * 4]) = v;
    }

    const int c0 = lane;
    const float b0 = B[c0];
    float b1 = 0.0f;
    if (DOUT == 128) b1 = B[c0 + 64];

    for (int rg = blockIdx.x * 16; rg < n; rg += gridDim.x * 16) {
        __syncthreads();
        for (int i = tid; i < 16 * 32; i += 256) {
            int r = i >> 5, q = i & 31;
            int row = rg + r;
            float4 v = make_float4(0.f, 0.f, 0.f, 0.f);
            if (row < n) v = reinterpret_cast<const float4*>(X + (size_t)row * 128)[q];
            if (RELU) {
                v.x = fmaxf(v.x, 0.f); v.y = fmaxf(v.y, 0.f);
                v.z = fmaxf(v.z, 0.f); v.w = fmaxf(v.w, 0.f);
            }
            *reinterpret_cast<float4*>(&sX[r * 128 + q * 4]) = v;
        }
        __syncthreads();

        float acc0[4] = {0.f, 0.f, 0.f, 0.f};
        float acc1[4] = {0.f, 0.f, 0.f, 0.f};
        // unroll 4 (NOT full): full unroll spilled to scratch (R1: VGPR=256,
        // 864 MB scratch traffic, 400us/dispatch).
#pragma unroll 4
        for (int q = 0; q < 32; q++) {
            int qs0 = (q + c0) & 31;
            float4 w0 = *reinterpret_cast<const float4*>(&sW[c0 * 128 + qs0 * 4]);
            float4 w1 = w0;
            if (DOUT == 128)
                w1 = *reinterpret_cast<const float4*>(&sW[(c0 + 64) * 128 + qs0 * 4]);
#pragma unroll
            for (int r = 0; r < 4; r++) {
                float4 xv = *reinterpret_cast<const float4*>(&sX[(wave * 4 + r) * 128 + q * 4]);
                acc0[r] += xv.x * w0.x + xv.y * w0.y + xv.z * w0.z + xv.w * w0.w;
                if (DOUT == 128)
                    acc1[r] += xv.x * w1.x + xv.y * w1.y + xv.z * w1.z + xv.w * w1.w;
            }
        }
#pragma unroll
        for (int r = 0; r < 4; r++) {
            int row = rg + wave * 4 + r;
            float v0 = acc0[r] + b0;
            float v1 = acc1[r] + b1;
            float ss = v0 * v0;
            if (DOUT == 128) ss += v1 * v1;
            float tot = wave_reduce_sum(ss);
            if (row < n) {
                H[(size_t)row * DOUT + c0] = v0;
                if (DOUT == 128) H[(size_t)row * DOUT + c0 + 64] = v1;
                if (lane == 0) {
                    float nrm = sqrtf(tot);
                    float ri = 1.0f / fmaxf(nrm, 1e-12f);
                    float s = nrm * ri;
                    rinv[row] = ri;
                    exself[row] = expf(s * s);
                }
            }
        }
    }
}

// ---------------- Fused attention aggregation (one wave per node) ----------------
// out[i] = (exself*h[i] + sum_e exp(cos(i,src_e)) * h[src_e]) / (exself + sum_e exp(...))
// Edge loop unrolled x4: 4 outstanding gathers/wave (MLP), 4-wide interleaved
// shuffle reduce (ILP), __expf on the chain.
__global__ __launch_bounds__(256) void k_agg128(
    const float* __restrict__ H, const float* __restrict__ rinv, const float* __restrict__ exself,
    const int* __restrict__ rowst, const int* __restrict__ csrc,
    float* __restrict__ OUT, int n)
{
    int wave = threadIdx.x >> 6, lane = threadIdx.x & 63;
    int node = blockIdx.x * 4 + wave;
    if (node >= n) return;
    float2 hi = *reinterpret_cast<const float2*>(&H[(size_t)node * 128 + lane * 2]);
    float ri = rinv[node];
    float2 hin = make_float2(hi.x * ri, hi.y * ri);   // pre-normalized own row
    float es = exself[node];
    float denom = es;
    float2 acc = make_float2(es * hi.x, es * hi.y);
    int p0 = rowst[node], p1 = rowst[node + 1];
    int p = p0;
    for (; p + 4 <= p1; p += 4) {
        int s[4]; float2 hs[4]; float rv[4]; float d[4];
#pragma unroll
        for (int k = 0; k < 4; k++) s[k] = csrc[p + k];
#pragma unroll
        for (int k = 0; k < 4; k++)
            hs[k] = *reinterpret_cast<const float2*>(&H[(size_t)s[k] * 128 + lane * 2]);
#pragma unroll
        for (int k = 0; k < 4; k++) rv[k] = rinv[s[k]];
#pragma unroll
        for (int k = 0; k < 4; k++) d[k] = hs[k].x * hin.x + hs[k].y * hin.y;
#pragma unroll
        for (int m = 32; m > 0; m >>= 1) {
#pragma unroll
            for (int k = 0; k < 4; k++) d[k] += __shfl_xor(d[k], m, 64);
        }
        float ex[4];
#pragma unroll
        for (int k = 0; k < 4; k++) ex[k] = __expf(d[k] * rv[k]);
        denom += (ex[0] + ex[1]) + (ex[2] + ex[3]);
#pragma unroll
        for (int k = 0; k < 4; k++) {
            acc.x += ex[k] * hs[k].x;
            acc.y += ex[k] * hs[k].y;
        }
    }
    for (; p < p1; p++) {
        int s = csrc[p];
        float2 hs = *reinterpret_cast<const float2*>(&H[(size_t)s * 128 + lane * 2]);
        float d = wave_reduce_sum(hs.x * hin.x + hs.y * hin.y);
        float ex = __expf(d * rinv[s]);
        denom += ex;
        acc.x += ex * hs.x;
        acc.y += ex * hs.y;
    }
    float inv = 1.0f / denom;
    *reinterpret_cast<float2*>(&OUT[(size_t)node * 128 + lane * 2]) =
        make_float2(acc.x * inv, acc.y * inv);
}

// D=64 variant with fused log_softmax epilogue (64 lanes = 64 classes)
__global__ __launch_bounds__(256) void k_agg64_lsm(
    const float* __restrict__ H, const float* __restrict__ rinv, const float* __restrict__ exself,
    const int* __restrict__ rowst, const int* __restrict__ csrc,
    float* __restrict__ OUT, int n)
{
    int wave = threadIdx.x >> 6, lane = threadIdx.x & 63;
    int node = blockIdx.x * 4 + wave;
    if (node >= n) return;
    float hi = H[(size_t)node * 64 + lane];
    float ri = rinv[node];
    float hin = hi * ri;
    float es = exself[node];
    float denom = es;
    float acc = es * hi;
    int p0 = rowst[node], p1 = rowst[node + 1];
    int p = p0;
    for (; p + 4 <= p1; p += 4) {
        int s[4]; float hs[4]; float rv[4]; float d[4];
#pragma unroll
        for (int k = 0; k < 4; k++) s[k] = csrc[p + k];
#pragma unroll
        for (int k = 0; k < 4; k++) hs[k] = H[(size_t)s[k] * 64 + lane];
#pragma unroll
        for (int k = 0; k < 4; k++) rv[k] = rinv[s[k]];
#pragma unroll
        for (int k = 0; k < 4; k++) d[k] = hs[k] * hin;
#pragma unroll
        for (int m = 32; m > 0; m >>= 1) {
#pragma unroll
            for (int k = 0; k < 4; k++) d[k] += __shfl_xor(d[k], m, 64);
        }
        float ex[4];
#pragma unroll
        for (int k = 0; k < 4; k++) ex[k] = __expf(d[k] * rv[k]);
        denom += (ex[0] + ex[1]) + (ex[2] + ex[3]);
#pragma unroll
        for (int k = 0; k < 4; k++) acc += ex[k] * hs[k];
    }
    for (; p < p1; p++) {
        int s = csrc[p];
        float hs = H[(size_t)s * 64 + lane];
        float d = wave_reduce_sum(hs * hin);
        float ex = __expf(d * rinv[s]);
        denom += ex;
        acc += ex * hs;
    }
    float val = acc / denom;
    float m = wave_reduce_max(val);
    float se = wave_reduce_sum(__expf(val - m));
    OUT[(size_t)node * 64 + lane] = val - m - logf(se);
}

extern "C" void kernel_launch(void* const* d_in, const int* in_sizes, int n_in,
                              void* d_out, int out_size, void* d_ws, size_t ws_size,
                              hipStream_t stream)
{
    const float* x  = (const float*)d_in[0];
    const int*   ei = (const int*)d_in[1];
    const float* W1 = (const float*)d_in[2];
    const float* b1 = (const float*)d_in[3];
    const float* W2 = (const float*)d_in[4];
    const float* b2 = (const float*)d_in[5];
    const float* W3 = (const float*)d_in[6];
    const float* b3 = (const float*)d_in[7];
    float* out = (float*)d_out;

    const int n = in_sizes[0] / 128;
    const int e = in_sizes[1] / 2;
    const int* esrc = ei;
    const int* edst = ei + e;

    char* w = (char*)d_ws;
    float* h    = (float*)w;  w += (size_t)n * 128 * sizeof(float);
    float* conv = (float*)w;  w += (size_t)n * 128 * sizeof(float);
    float* rinv = (float*)w;  w += (size_t)n * sizeof(float);
    float* exs  = (float*)w;  w += (size_t)n * sizeof(float);
    int* rowst  = (int*)w;    w += (size_t)(n + 1) * sizeof(int);
    int* cursor = (int*)w;    w += (size_t)n * sizeof(int);
    int* deg    = (int*)w;    w += (size_t)n * sizeof(int);
    int* incl   = (int*)w;    w += (size_t)n * sizeof(int);
    int* bsum   = (int*)w;    w += 64 * sizeof(int);
    int* csrc   = (int*)w;    w += (size_t)e * sizeof(int);

    const int nb = (n + 1023) / 1024;   // 49 for n=50000 (<= 64)

    // ---- CSR build (shared by all 3 layers) ----
    hipMemsetAsync(deg, 0, (size_t)n * sizeof(int), stream);
    k_hist<<<(e + 255) / 256, 256, 0, stream>>>(edst, deg, e);
    k_scan_blk<<<nb, 1024, 0, stream>>>(deg, incl, bsum, n);
    k_scan_top<<<1, 64, 0, stream>>>(bsum, nb);
    k_scan_fin<<<nb, 1024, 0, stream>>>(deg, incl, bsum, rowst, cursor, n);
    k_fill<<<(e + 255) / 256, 256, 0, stream>>>(esrc, edst, cursor, csrc, e);

    const int lgrid = (n + 15) / 16;
    const int agrid = (n + 3) / 4;

    // layer 1
    k_linear<128, false><<<lgrid, 256, 0, stream>>>(x, W1, b1, h, rinv, exs, n);
    k_agg128<<<agrid, 256, 0, stream>>>(h, rinv, exs, rowst, csrc, conv, n);
    // layer 2 (ReLU folded into input read)
    k_linear<128, true><<<lgrid, 256, 0, stream>>>(conv, W2, b2, h, rinv, exs, n);
    k_agg128<<<agrid, 256, 0, stream>>>(h, rinv, exs, rowst, csrc, conv, n);
    // layer 3 + log_softmax
    k_linear<64, true><<<lgrid, 256, 0, stream>>>(conv, W3, b3, h, rinv, exs, n);
    k_agg64_lsm<<<agrid, 256, 0, stream>>>(h, rinv, exs, rowst, csrc, out, n);
}

// Round 4
// 409.766 us; speedup vs baseline: 3.2362x; 1.1212x over previous
//
#include <hip/hip_runtime.h>

typedef float f32x4 __attribute__((ext_vector_type(4)));
typedef short bf16x8 __attribute__((ext_vector_type(8)));

__device__ __forceinline__ float wave_reduce_sum(float v) {
#pragma unroll
    for (int m = 32; m > 0; m >>= 1) v += __shfl_xor(v, m, 64);
    return v;
}
__device__ __forceinline__ float wave_reduce_max(float v) {
#pragma unroll
    for (int m = 32; m > 0; m >>= 1) v = fmaxf(v, __shfl_xor(v, m, 64));
    return v;
}

__device__ __forceinline__ unsigned short bf16_rne(float x) {
    unsigned u = __float_as_uint(x);
    unsigned r = (u + 0x7FFFu + ((u >> 16) & 1u)) >> 16;
    return (unsigned short)r;
}

// ---------------- CSR build (by dst) ----------------
__global__ void k_hist(const int* __restrict__ dst, int* __restrict__ deg, int e) {
    int i = blockIdx.x * blockDim.x + threadIdx.x;
    if (i < e) atomicAdd(&deg[dst[i]], 1);
}

__global__ __launch_bounds__(1024) void k_scan_blk(
    const int* __restrict__ deg, int* __restrict__ incl, int* __restrict__ bsum, int n)
{
    int tid = threadIdx.x, lane = tid & 63, wv = tid >> 6;
    int gid = blockIdx.x * 1024 + tid;
    int x = (gid < n) ? deg[gid] : 0;
    int v = x;
#pragma unroll
    for (int off = 1; off < 64; off <<= 1) {
        int t = __shfl_up(v, off, 64);
        if (lane >= off) v += t;
    }
    __shared__ int wsum[16];
    if (lane == 63) wsum[wv] = v;
    __syncthreads();
    if (wv == 0) {
        int w = (lane < 16) ? wsum[lane] : 0;
#pragma unroll
        for (int off = 1; off < 16; off <<= 1) {
            int t = __shfl_up(w, off, 64);
            if (lane >= off) w += t;
        }
        if (lane < 16) wsum[lane] = w;
    }
    __syncthreads();
    if (wv > 0) v += wsum[wv - 1];
    if (gid < n) incl[gid] = v;
    if (tid == 1023) bsum[blockIdx.x] = v;
}

__global__ void k_scan_top(int* __restrict__ bsum, int nb) {
    int lane = threadIdx.x;
    int v = (lane < nb) ? bsum[lane] : 0;
#pragma unroll
    for (int off = 1; off < 64; off <<= 1) {
        int t = __shfl_up(v, off, 64);
        if (lane >= off) v += t;
    }
    if (lane < nb) bsum[lane] = v;
}

__global__ __launch_bounds__(1024) void k_scan_fin(
    const int* __restrict__ deg, const int* __restrict__ incl, const int* __restrict__ bsum,
    int* __restrict__ rowst, int* __restrict__ cursor, int n)
{
    int gid = blockIdx.x * 1024 + threadIdx.x;
    int boff = (blockIdx.x > 0) ? bsum[blockIdx.x - 1] : 0;
    if (gid < n) {
        int r = boff + incl[gid] - deg[gid];
        rowst[gid] = r;
        cursor[gid] = r;
        if (gid == n - 1) rowst[n] = boff + incl[gid];
    }
}

__global__ void k_fill(const int* __restrict__ src, const int* __restrict__ dst,
                       int* __restrict__ cursor, int* __restrict__ csrc, int e) {
    int i = blockIdx.x * blockDim.x + threadIdx.x;
    if (i < e) {
        int p = atomicAdd(&cursor[dst[i]], 1);
        csrc[p] = src[i];
    }
}

// ---------------- W hi/lo bf16 split (once per layer, L2-resident) ----------------
__global__ void k_wsplit(const float* __restrict__ W, short* __restrict__ hi,
                         short* __restrict__ lo, int count) {
    int i = blockIdx.x * blockDim.x + threadIdx.x;
    if (i < count) {
        float v = W[i];
        unsigned short h = bf16_rne(v);
        float hf = __uint_as_float(((unsigned)h) << 16);
        unsigned short l = bf16_rne(v - hf);
        hi[i] = (short)h;
        lo[i] = (short)l;
    }
}

// ---------------- MFMA Linear + L2-norm prep ----------------
// One wave = 16 rows x DOUT cols. X split to bf16 hi/lo in-register; W pre-split.
// C = (Ahi+Alo)(Bhi+Blo) ~= Ahi*Bhi + Alo*Bhi + Ahi*Blo  (fp32-accurate)
// Fragment layouts (m89-verified): A[l&15][(l>>4)*8+j], B[k=(l>>4)*8+j][l&15],
// D row=(l>>4)*4+reg, col=l&15.
template <int DOUT, bool RELU>
__global__ __launch_bounds__(256) void k_linear_mfma(
    const float* __restrict__ X, const short* __restrict__ Whi, const short* __restrict__ Wlo,
    const float* __restrict__ B, float* __restrict__ H,
    float* __restrict__ rinv, float* __restrict__ exself, int n)
{
    constexpr int NT = DOUT / 16;
    const int lane = threadIdx.x & 63;
    const int wid = blockIdx.x * 4 + (threadIdx.x >> 6);
    const int nw = (n + 15) >> 4;
    if (wid >= nw) return;
    const int rg = wid << 4;
    const int r16 = lane & 15, kh = lane >> 4;

    f32x4 acc[NT];
#pragma unroll
    for (int t = 0; t < NT; t++) acc[t] = (f32x4){0.f, 0.f, 0.f, 0.f};

    const float* xp = X + (size_t)(rg + r16) * 128 + kh * 8;

#pragma unroll 1
    for (int ks = 0; ks < 4; ks++) {
        float4 xa = *reinterpret_cast<const float4*>(xp + ks * 32);
        float4 xb = *reinterpret_cast<const float4*>(xp + ks * 32 + 4);
        float xv[8] = {xa.x, xa.y, xa.z, xa.w, xb.x, xb.y, xb.z, xb.w};
        bf16x8 ahi, alo;
#pragma unroll
        for (int j = 0; j < 8; j++) {
            float v = xv[j];
            if (RELU) v = fmaxf(v, 0.f);
            unsigned short h = bf16_rne(v);
            float hf = __uint_as_float(((unsigned)h) << 16);
            unsigned short l = bf16_rne(v - hf);
            ahi[j] = (short)h;
            alo[j] = (short)l;
        }
        const int wo = kh * 8 + ks * 32;
#pragma unroll
        for (int t = 0; t < NT; t++) {
            const short* wh = Whi + (size_t)(t * 16 + r16) * 128 + wo;
            const short* wl = Wlo + (size_t)(t * 16 + r16) * 128 + wo;
            bf16x8 bh = *reinterpret_cast<const bf16x8*>(wh);
            bf16x8 bl = *reinterpret_cast<const bf16x8*>(wl);
            acc[t] = __builtin_amdgcn_mfma_f32_16x16x32_bf16(ahi, bh, acc[t], 0, 0, 0);
            acc[t] = __builtin_amdgcn_mfma_f32_16x16x32_bf16(alo, bh, acc[t], 0, 0, 0);
            acc[t] = __builtin_amdgcn_mfma_f32_16x16x32_bf16(ahi, bl, acc[t], 0, 0, 0);
        }
    }

    // bias + sum-of-squares per row (row = kh*4 + r, held by 16-lane group)
    float ss[4] = {0.f, 0.f, 0.f, 0.f};
#pragma unroll
    for (int t = 0; t < NT; t++) {
        float bs = B[t * 16 + r16];
#pragma unroll
        for (int r = 0; r < 4; r++) {
            float v = acc[t][r] + bs;
            acc[t][r] = v;
            ss[r] += v * v;
        }
    }
#pragma unroll
    for (int m = 8; m > 0; m >>= 1) {
#pragma unroll
        for (int r = 0; r < 4; r++) ss[r] += __shfl_xor(ss[r], m, 64);
    }
#pragma unroll
    for (int t = 0; t < NT; t++) {
#pragma unroll
        for (int r = 0; r < 4; r++) {
            int grow = rg + kh * 4 + r;
            if (grow < n) H[(size_t)grow * DOUT + t * 16 + r16] = acc[t][r];
        }
    }
    if (r16 == 0) {
#pragma unroll
        for (int r = 0; r < 4; r++) {
            int grow = rg + kh * 4 + r;
            if (grow < n) {
                float nrm = sqrtf(ss[r]);
                float ri = 1.0f / fmaxf(nrm, 1e-12f);
                float s = nrm * ri;
                rinv[grow] = ri;
                exself[grow] = __expf(s * s);
            }
        }
    }
}

// ---------------- Fused attention aggregation (one wave per node) ----------------
__global__ __launch_bounds__(256) void k_agg128(
    const float* __restrict__ H, const float* __restrict__ rinv, const float* __restrict__ exself,
    const int* __restrict__ rowst, const int* __restrict__ csrc,
    float* __restrict__ OUT, int n)
{
    int wave = threadIdx.x >> 6, lane = threadIdx.x & 63;
    int node = blockIdx.x * 4 + wave;
    if (node >= n) return;
    float2 hi = *reinterpret_cast<const float2*>(&H[(size_t)node * 128 + lane * 2]);
    float ri = rinv[node];
    float2 hin = make_float2(hi.x * ri, hi.y * ri);
    float es = exself[node];
    float denom = es;
    float2 acc = make_float2(es * hi.x, es * hi.y);
    int p0 = rowst[node], p1 = rowst[node + 1];
    int p = p0;
    for (; p + 8 <= p1; p += 8) {
        int s[8]; float2 hs[8]; float rv[8]; float d[8];
#pragma unroll
        for (int k = 0; k < 8; k++) s[k] = csrc[p + k];
#pragma unroll
        for (int k = 0; k < 8; k++)
            hs[k] = *reinterpret_cast<const float2*>(&H[(size_t)s[k] * 128 + lane * 2]);
#pragma unroll
        for (int k = 0; k < 8; k++) rv[k] = rinv[s[k]];
#pragma unroll
        for (int k = 0; k < 8; k++) d[k] = hs[k].x * hin.x + hs[k].y * hin.y;
#pragma unroll
        for (int m = 32; m > 0; m >>= 1) {
#pragma unroll
            for (int k = 0; k < 8; k++) d[k] += __shfl_xor(d[k], m, 64);
        }
#pragma unroll
        for (int k = 0; k < 8; k++) {
            float ex = __expf(d[k] * rv[k]);
            denom += ex;
            acc.x += ex * hs[k].x;
            acc.y += ex * hs[k].y;
        }
    }
    for (; p + 4 <= p1; p += 4) {
        int s[4]; float2 hs[4]; float rv[4]; float d[4];
#pragma unroll
        for (int k = 0; k < 4; k++) s[k] = csrc[p + k];
#pragma unroll
        for (int k = 0; k < 4; k++)
            hs[k] = *reinterpret_cast<const float2*>(&H[(size_t)s[k] * 128 + lane * 2]);
#pragma unroll
        for (int k = 0; k < 4; k++) rv[k] = rinv[s[k]];
#pragma unroll
        for (int k = 0; k < 4; k++) d[k] = hs[k].x * hin.x + hs[k].y * hin.y;
#pragma unroll
        for (int m = 32; m > 0; m >>= 1) {
#pragma unroll
            for (int k = 0; k < 4; k++) d[k] += __shfl_xor(d[k], m, 64);
        }
#pragma unroll
        for (int k = 0; k < 4; k++) {
            float ex = __expf(d[k] * rv[k]);
            denom += ex;
            acc.x += ex * hs[k].x;
            acc.y += ex * hs[k].y;
        }
    }
    for (; p < p1; p++) {
        int s = csrc[p];
        float2 hs = *reinterpret_cast<const float2*>(&H[(size_t)s * 128 + lane * 2]);
        float d = wave_reduce_sum(hs.x * hin.x + hs.y * hin.y);
        float ex = __expf(d * rinv[s]);
        denom += ex;
        acc.x += ex * hs.x;
        acc.y += ex * hs.y;
    }
    float inv = 1.0f / denom;
    *reinterpret_cast<float2*>(&OUT[(size_t)node * 128 + lane * 2]) =
        make_float2(acc.x * inv, acc.y * inv);
}

__global__ __launch_bounds__(256) void k_agg64_lsm(
    const float* __restrict__ H, const float* __restrict__ rinv, const float* __restrict__ exself,
    const int* __restrict__ rowst, const int* __restrict__ csrc,
    float* __restrict__ OUT, int n)
{
    int wave = threadIdx.x >> 6, lane = threadIdx.x & 63;
    int node = blockIdx.x * 4 + wave;
    if (node >= n) return;
    float hi = H[(size_t)node * 64 + lane];
    float ri = rinv[node];
    float hin = hi * ri;
    float es = exself[node];
    float denom = es;
    float acc = es * hi;
    int p0 = rowst[node], p1 = rowst[node + 1];
    int p = p0;
    for (; p + 8 <= p1; p += 8) {
        int s[8]; float hs[8]; float rv[8]; float d[8];
#pragma unroll
        for (int k = 0; k < 8; k++) s[k] = csrc[p + k];
#pragma unroll
        for (int k = 0; k < 8; k++) hs[k] = H[(size_t)s[k] * 64 + lane];
#pragma unroll
        for (int k = 0; k < 8; k++) rv[k] = rinv[s[k]];
#pragma unroll
        for (int k = 0; k < 8; k++) d[k] = hs[k] * hin;
#pragma unroll
        for (int m = 32; m > 0; m >>= 1) {
#pragma unroll
            for (int k = 0; k < 8; k++) d[k] += __shfl_xor(d[k], m, 64);
        }
#pragma unroll
        for (int k = 0; k < 8; k++) {
            float ex = __expf(d[k] * rv[k]);
            denom += ex;
            acc += ex * hs[k];
        }
    }
    for (; p < p1; p++) {
        int s = csrc[p];
        float hs = H[(size_t)s * 64 + lane];
        float d = wave_reduce_sum(hs * hin);
        float ex = __expf(d * rinv[s]);
        denom += ex;
        acc += ex * hs;
    }
    float val = acc / denom;
    float m = wave_reduce_max(val);
    float se = wave_reduce_sum(__expf(val - m));
    OUT[(size_t)node * 64 + lane] = val - m - logf(se);
}

extern "C" void kernel_launch(void* const* d_in, const int* in_sizes, int n_in,
                              void* d_out, int out_size, void* d_ws, size_t ws_size,
                              hipStream_t stream)
{
    const float* x  = (const float*)d_in[0];
    const int*   ei = (const int*)d_in[1];
    const float* W1 = (const float*)d_in[2];
    const float* b1 = (const float*)d_in[3];
    const float* W2 = (const float*)d_in[4];
    const float* b2 = (const float*)d_in[5];
    const float* W3 = (const float*)d_in[6];
    const float* b3 = (const float*)d_in[7];
    float* out = (float*)d_out;

    const int n = in_sizes[0] / 128;
    const int e = in_sizes[1] / 2;
    const int* esrc = ei;
    const int* edst = ei + e;

    char* w = (char*)d_ws;
    float* h    = (float*)w;  w += (size_t)n * 128 * sizeof(float);
    float* conv = (float*)w;  w += (size_t)n * 128 * sizeof(float);
    float* rinv = (float*)w;  w += (size_t)n * sizeof(float);
    float* exs  = (float*)w;  w += (size_t)n * sizeof(float);
    int* rowst  = (int*)w;    w += (size_t)(n + 1) * sizeof(int);
    int* cursor = (int*)w;    w += (size_t)n * sizeof(int);
    int* deg    = (int*)w;    w += (size_t)n * sizeof(int);
    int* incl   = (int*)w;    w += (size_t)n * sizeof(int);
    int* bsum   = (int*)w;    w += 64 * sizeof(int);
    int* csrc   = (int*)w;    w += (size_t)e * sizeof(int);
    short* w1h  = (short*)w;  w += 128 * 128 * sizeof(short);
    short* w1l  = (short*)w;  w += 128 * 128 * sizeof(short);
    short* w2h  = (short*)w;  w += 128 * 128 * sizeof(short);
    short* w2l  = (short*)w;  w += 128 * 128 * sizeof(short);
    short* w3h  = (short*)w;  w += 64 * 128 * sizeof(short);
    short* w3l  = (short*)w;  w += 64 * 128 * sizeof(short);

    const int nb = (n + 1023) / 1024;

    // ---- CSR build (shared by all 3 layers) + W splits ----
    hipMemsetAsync(deg, 0, (size_t)n * sizeof(int), stream);
    k_hist<<<(e + 255) / 256, 256, 0, stream>>>(edst, deg, e);
    k_wsplit<<<64, 256, 0, stream>>>(W1, w1h, w1l, 128 * 128);
    k_wsplit<<<64, 256, 0, stream>>>(W2, w2h, w2l, 128 * 128);
    k_wsplit<<<32, 256, 0, stream>>>(W3, w3h, w3l, 64 * 128);
    k_scan_blk<<<nb, 1024, 0, stream>>>(deg, incl, bsum, n);
    k_scan_top<<<1, 64, 0, stream>>>(bsum, nb);
    k_scan_fin<<<nb, 1024, 0, stream>>>(deg, incl, bsum, rowst, cursor, n);
    k_fill<<<(e + 255) / 256, 256, 0, stream>>>(esrc, edst, cursor, csrc, e);

    const int nwv = (n + 15) / 16;
    const int lgrid = (nwv + 3) / 4;
    const int agrid = (n + 3) / 4;

    // layer 1
    k_linear_mfma<128, false><<<lgrid, 256, 0, stream>>>(x, w1h, w1l, b1, h, rinv, exs, n);
    k_agg128<<<agrid, 256, 0, stream>>>(h, rinv, exs, rowst, csrc, conv, n);
    // layer 2 (ReLU folded into A-fragment load)
    k_linear_mfma<128, true><<<lgrid, 256, 0, stream>>>(conv, w2h, w2l, b2, h, rinv, exs, n);
    k_agg128<<<agrid, 256, 0, stream>>>(h, rinv, exs, rowst, csrc, conv, n);
    // layer 3 + log_softmax
    k_linear_mfma<64, true><<<lgrid, 256, 0, stream>>>(conv, w3h, w3l, b3, h, rinv, exs, n);
    k_agg64_lsm<<<agrid, 256, 0, stream>>>(h, rinv, exs, rowst, csrc, out, n);
}

// Round 5
// 363.023 us; speedup vs baseline: 3.6529x; 1.1288x over previous
//
#include <hip/hip_runtime.h>

typedef float f32x4 __attribute__((ext_vector_type(4)));
typedef short bf16x8 __attribute__((ext_vector_type(8)));

__device__ __forceinline__ float wave_reduce_sum(float v) {
#pragma unroll
    for (int m = 32; m > 0; m >>= 1) v += __shfl_xor(v, m, 64);
    return v;
}

__device__ __forceinline__ unsigned short bf16_rne(float x) {
    unsigned u = __float_as_uint(x);
    unsigned r = (u + 0x7FFFu + ((u >> 16) & 1u)) >> 16;
    return (unsigned short)r;
}

// ---------------- CSR build (by dst) ----------------
__global__ void k_hist(const int* __restrict__ dst, int* __restrict__ deg, int e) {
    int i = blockIdx.x * blockDim.x + threadIdx.x;
    if (i < e) atomicAdd(&deg[dst[i]], 1);
}

__global__ __launch_bounds__(1024) void k_scan_blk(
    const int* __restrict__ deg, int* __restrict__ incl, int* __restrict__ bsum, int n)
{
    int tid = threadIdx.x, lane = tid & 63, wv = tid >> 6;
    int gid = blockIdx.x * 1024 + tid;
    int x = (gid < n) ? deg[gid] : 0;
    int v = x;
#pragma unroll
    for (int off = 1; off < 64; off <<= 1) {
        int t = __shfl_up(v, off, 64);
        if (lane >= off) v += t;
    }
    __shared__ int wsum[16];
    if (lane == 63) wsum[wv] = v;
    __syncthreads();
    if (wv == 0) {
        int w = (lane < 16) ? wsum[lane] : 0;
#pragma unroll
        for (int off = 1; off < 16; off <<= 1) {
            int t = __shfl_up(w, off, 64);
            if (lane >= off) w += t;
        }
        if (lane < 16) wsum[lane] = w;
    }
    __syncthreads();
    if (wv > 0) v += wsum[wv - 1];
    if (gid < n) incl[gid] = v;
    if (tid == 1023) bsum[blockIdx.x] = v;
}

__global__ void k_scan_top(int* __restrict__ bsum, int nb) {
    int lane = threadIdx.x;
    int v = (lane < nb) ? bsum[lane] : 0;
#pragma unroll
    for (int off = 1; off < 64; off <<= 1) {
        int t = __shfl_up(v, off, 64);
        if (lane >= off) v += t;
    }
    if (lane < nb) bsum[lane] = v;
}

__global__ __launch_bounds__(1024) void k_scan_fin(
    const int* __restrict__ deg, const int* __restrict__ incl, const int* __restrict__ bsum,
    int* __restrict__ rowst, int* __restrict__ cursor, int n)
{
    int gid = blockIdx.x * 1024 + threadIdx.x;
    int boff = (blockIdx.x > 0) ? bsum[blockIdx.x - 1] : 0;
    if (gid < n) {
        int r = boff + incl[gid] - deg[gid];
        rowst[gid] = r;
        cursor[gid] = r;
        if (gid == n - 1) rowst[n] = boff + incl[gid];
    }
}

__global__ void k_fill(const int* __restrict__ src, const int* __restrict__ dst,
                       int* __restrict__ cursor, int* __restrict__ csrc, int e) {
    int i = blockIdx.x * blockDim.x + threadIdx.x;
    if (i < e) {
        int p = atomicAdd(&cursor[dst[i]], 1);
        csrc[p] = src[i];
    }
}

// ---------------- W hi/lo bf16 split ----------------
__global__ void k_wsplit(const float* __restrict__ W, short* __restrict__ hi,
                         short* __restrict__ lo, int count) {
    int i = blockIdx.x * blockDim.x + threadIdx.x;
    if (i < count) {
        float v = W[i];
        unsigned short h = bf16_rne(v);
        float hf = __uint_as_float(((unsigned)h) << 16);
        unsigned short l = bf16_rne(v - hf);
        hi[i] = (short)h;
        lo[i] = (short)l;
    }
}

// ---------------- MFMA Linear + L2-norm prep ----------------
template <int DOUT, bool RELU>
__global__ __launch_bounds__(256) void k_linear_mfma(
    const float* __restrict__ X, const short* __restrict__ Whi, const short* __restrict__ Wlo,
    const float* __restrict__ B, float* __restrict__ H,
    float* __restrict__ rinv, float* __restrict__ exself, int n)
{
    constexpr int NT = DOUT / 16;
    const int lane = threadIdx.x & 63;
    const int wid = blockIdx.x * 4 + (threadIdx.x >> 6);
    const int nw = (n + 15) >> 4;
    if (wid >= nw) return;
    const int rg = wid << 4;
    const int r16 = lane & 15, kh = lane >> 4;

    f32x4 acc[NT];
#pragma unroll
    for (int t = 0; t < NT; t++) acc[t] = (f32x4){0.f, 0.f, 0.f, 0.f};

    const float* xp = X + (size_t)(rg + r16) * 128 + kh * 8;

#pragma unroll 1
    for (int ks = 0; ks < 4; ks++) {
        float4 xa = *reinterpret_cast<const float4*>(xp + ks * 32);
        float4 xb = *reinterpret_cast<const float4*>(xp + ks * 32 + 4);
        float xv[8] = {xa.x, xa.y, xa.z, xa.w, xb.x, xb.y, xb.z, xb.w};
        bf16x8 ahi, alo;
#pragma unroll
        for (int j = 0; j < 8; j++) {
            float v = xv[j];
            if (RELU) v = fmaxf(v, 0.f);
            unsigned short h = bf16_rne(v);
            float hf = __uint_as_float(((unsigned)h) << 16);
            unsigned short l = bf16_rne(v - hf);
            ahi[j] = (short)h;
            alo[j] = (short)l;
        }
        const int wo = kh * 8 + ks * 32;
#pragma unroll
        for (int t = 0; t < NT; t++) {
            const short* wh = Whi + (size_t)(t * 16 + r16) * 128 + wo;
            const short* wl = Wlo + (size_t)(t * 16 + r16) * 128 + wo;
            bf16x8 bh = *reinterpret_cast<const bf16x8*>(wh);
            bf16x8 bl = *reinterpret_cast<const bf16x8*>(wl);
            acc[t] = __builtin_amdgcn_mfma_f32_16x16x32_bf16(ahi, bh, acc[t], 0, 0, 0);
            acc[t] = __builtin_amdgcn_mfma_f32_16x16x32_bf16(alo, bh, acc[t], 0, 0, 0);
            acc[t] = __builtin_amdgcn_mfma_f32_16x16x32_bf16(ahi, bl, acc[t], 0, 0, 0);
        }
    }

    float ss[4] = {0.f, 0.f, 0.f, 0.f};
#pragma unroll
    for (int t = 0; t < NT; t++) {
        float bs = B[t * 16 + r16];
#pragma unroll
        for (int r = 0; r < 4; r++) {
            float v = acc[t][r] + bs;
            acc[t][r] = v;
            ss[r] += v * v;
        }
    }
#pragma unroll
    for (int m = 8; m > 0; m >>= 1) {
#pragma unroll
        for (int r = 0; r < 4; r++) ss[r] += __shfl_xor(ss[r], m, 64);
    }
#pragma unroll
    for (int t = 0; t < NT; t++) {
#pragma unroll
        for (int r = 0; r < 4; r++) {
            int grow = rg + kh * 4 + r;
            if (grow < n) H[(size_t)grow * DOUT + t * 16 + r16] = acc[t][r];
        }
    }
    if (r16 == 0) {
#pragma unroll
        for (int r = 0; r < 4; r++) {
            int grow = rg + kh * 4 + r;
            if (grow < n) {
                float nrm = sqrtf(ss[r]);
                float ri = 1.0f / fmaxf(nrm, 1e-12f);
                float s = nrm * ri;
                rinv[grow] = ri;
                exself[grow] = __expf(s * s);
            }
        }
    }
}

// ---------------- Fused attention aggregation ----------------
// 16-lane groups: 4 edges processed per wave concurrently. Each lane holds
// 8 dims (D=128). dot=8 FMA serves 4 edges; reduce = 4 shfl within group;
// exp once per wave serves 4 edges. Cross-group combine once per node.
__global__ __launch_bounds__(256) void k_agg128(
    const float* __restrict__ H, const float* __restrict__ rinv, const float* __restrict__ exself,
    const int* __restrict__ rowst, const int* __restrict__ csrc,
    float* __restrict__ OUT, int n)
{
    const int wave = threadIdx.x >> 6, lane = threadIdx.x & 63;
    const int node = blockIdx.x * 4 + wave;
    if (node >= n) return;
    const int g = lane >> 4;      // edge slot 0..3
    const int t = lane & 15;      // dims [t*8, t*8+8)

    const float* hp = H + (size_t)node * 128 + t * 8;
    float4 h0 = *reinterpret_cast<const float4*>(hp);
    float4 h1 = *reinterpret_cast<const float4*>(hp + 4);
    float ri = rinv[node];
    float hn[8] = {h0.x * ri, h0.y * ri, h0.z * ri, h0.w * ri,
                   h1.x * ri, h1.y * ri, h1.z * ri, h1.w * ri};
    float es = exself[node];
    float acc[8];
    float denom;
    if (g == 0) {
        acc[0] = es * h0.x; acc[1] = es * h0.y; acc[2] = es * h0.z; acc[3] = es * h0.w;
        acc[4] = es * h1.x; acc[5] = es * h1.y; acc[6] = es * h1.z; acc[7] = es * h1.w;
        denom = es;
    } else {
#pragma unroll
        for (int j = 0; j < 8; j++) acc[j] = 0.f;
        denom = 0.f;
    }

    const int p0 = rowst[node], p1 = rowst[node + 1];
    const int iters = (p1 - p0 + 3) >> 2;
    int it = 0;
    for (; it + 2 <= iters; it += 2) {
        int pA = p0 + it * 4 + g, pB = pA + 4;
        bool vA = pA < p1, vB = pB < p1;
        int sA = vA ? csrc[pA] : node;
        int sB = vB ? csrc[pB] : node;
        const float* pa = H + (size_t)sA * 128 + t * 8;
        const float* pb = H + (size_t)sB * 128 + t * 8;
        float4 a0 = *reinterpret_cast<const float4*>(pa);
        float4 a1 = *reinterpret_cast<const float4*>(pa + 4);
        float4 b0 = *reinterpret_cast<const float4*>(pb);
        float4 b1 = *reinterpret_cast<const float4*>(pb + 4);
        float rA = rinv[sA], rB = rinv[sB];
        float av[8] = {a0.x, a0.y, a0.z, a0.w, a1.x, a1.y, a1.z, a1.w};
        float bv[8] = {b0.x, b0.y, b0.z, b0.w, b1.x, b1.y, b1.z, b1.w};
        float dA = 0.f, dB = 0.f;
#pragma unroll
        for (int j = 0; j < 8; j++) { dA += av[j] * hn[j]; dB += bv[j] * hn[j]; }
#pragma unroll
        for (int m = 8; m > 0; m >>= 1) {
            dA += __shfl_xor(dA, m, 64);
            dB += __shfl_xor(dB, m, 64);
        }
        float exA = vA ? __expf(dA * rA) : 0.f;
        float exB = vB ? __expf(dB * rB) : 0.f;
        denom += exA + exB;
#pragma unroll
        for (int j = 0; j < 8; j++) acc[j] += exA * av[j] + exB * bv[j];
    }
    for (; it < iters; it++) {
        int pA = p0 + it * 4 + g;
        bool vA = pA < p1;
        int sA = vA ? csrc[pA] : node;
        const float* pa = H + (size_t)sA * 128 + t * 8;
        float4 a0 = *reinterpret_cast<const float4*>(pa);
        float4 a1 = *reinterpret_cast<const float4*>(pa + 4);
        float rA = rinv[sA];
        float av[8] = {a0.x, a0.y, a0.z, a0.w, a1.x, a1.y, a1.z, a1.w};
        float dA = 0.f;
#pragma unroll
        for (int j = 0; j < 8; j++) dA += av[j] * hn[j];
#pragma unroll
        for (int m = 8; m > 0; m >>= 1) dA += __shfl_xor(dA, m, 64);
        float exA = vA ? __expf(dA * rA) : 0.f;
        denom += exA;
#pragma unroll
        for (int j = 0; j < 8; j++) acc[j] += exA * av[j];
    }

    // combine the 4 groups
#pragma unroll
    for (int j = 0; j < 8; j++) {
        acc[j] += __shfl_xor(acc[j], 16, 64);
        acc[j] += __shfl_xor(acc[j], 32, 64);
    }
    denom += __shfl_xor(denom, 16, 64);
    denom += __shfl_xor(denom, 32, 64);

    if (g == 0) {
        float inv = 1.0f / denom;
        float4 o0 = make_float4(acc[0] * inv, acc[1] * inv, acc[2] * inv, acc[3] * inv);
        float4 o1 = make_float4(acc[4] * inv, acc[5] * inv, acc[6] * inv, acc[7] * inv);
        float* op = OUT + (size_t)node * 128 + t * 8;
        *reinterpret_cast<float4*>(op) = o0;
        *reinterpret_cast<float4*>(op + 4) = o1;
    }
}

// D=64: 16-lane groups, 4 dims/lane, fused log_softmax epilogue
__global__ __launch_bounds__(256) void k_agg64_lsm(
    const float* __restrict__ H, const float* __restrict__ rinv, const float* __restrict__ exself,
    const int* __restrict__ rowst, const int* __restrict__ csrc,
    float* __restrict__ OUT, int n)
{
    const int wave = threadIdx.x >> 6, lane = threadIdx.x & 63;
    const int node = blockIdx.x * 4 + wave;
    if (node >= n) return;
    const int g = lane >> 4;
    const int t = lane & 15;

    const float* hp = H + (size_t)node * 64 + t * 4;
    float4 h0 = *reinterpret_cast<const float4*>(hp);
    float ri = rinv[node];
    float hn[4] = {h0.x * ri, h0.y * ri, h0.z * ri, h0.w * ri};
    float es = exself[node];
    float acc[4];
    float denom;
    if (g == 0) {
        acc[0] = es * h0.x; acc[1] = es * h0.y; acc[2] = es * h0.z; acc[3] = es * h0.w;
        denom = es;
    } else {
        acc[0] = acc[1] = acc[2] = acc[3] = 0.f;
        denom = 0.f;
    }

    const int p0 = rowst[node], p1 = rowst[node + 1];
    const int iters = (p1 - p0 + 3) >> 2;
    int it = 0;
    for (; it + 2 <= iters; it += 2) {
        int pA = p0 + it * 4 + g, pB = pA + 4;
        bool vA = pA < p1, vB = pB < p1;
        int sA = vA ? csrc[pA] : node;
        int sB = vB ? csrc[pB] : node;
        float4 a0 = *reinterpret_cast<const float4*>(H + (size_t)sA * 64 + t * 4);
        float4 b0 = *reinterpret_cast<const float4*>(H + (size_t)sB * 64 + t * 4);
        float rA = rinv[sA], rB = rinv[sB];
        float dA = a0.x * hn[0] + a0.y * hn[1] + a0.z * hn[2] + a0.w * hn[3];
        float dB = b0.x * hn[0] + b0.y * hn[1] + b0.z * hn[2] + b0.w * hn[3];
#pragma unroll
        for (int m = 8; m > 0; m >>= 1) {
            dA += __shfl_xor(dA, m, 64);
            dB += __shfl_xor(dB, m, 64);
        }
        float exA = vA ? __expf(dA * rA) : 0.f;
        float exB = vB ? __expf(dB * rB) : 0.f;
        denom += exA + exB;
        acc[0] += exA * a0.x + exB * b0.x;
        acc[1] += exA * a0.y + exB * b0.y;
        acc[2] += exA * a0.z + exB * b0.z;
        acc[3] += exA * a0.w + exB * b0.w;
    }
    for (; it < iters; it++) {
        int pA = p0 + it * 4 + g;
        bool vA = pA < p1;
        int sA = vA ? csrc[pA] : node;
        float4 a0 = *reinterpret_cast<const float4*>(H + (size_t)sA * 64 + t * 4);
        float rA = rinv[sA];
        float dA = a0.x * hn[0] + a0.y * hn[1] + a0.z * hn[2] + a0.w * hn[3];
#pragma unroll
        for (int m = 8; m > 0; m >>= 1) dA += __shfl_xor(dA, m, 64);
        float exA = vA ? __expf(dA * rA) : 0.f;
        denom += exA;
        acc[0] += exA * a0.x;
        acc[1] += exA * a0.y;
        acc[2] += exA * a0.z;
        acc[3] += exA * a0.w;
    }

#pragma unroll
    for (int j = 0; j < 4; j++) {
        acc[j] += __shfl_xor(acc[j], 16, 64);
        acc[j] += __shfl_xor(acc[j], 32, 64);
    }
    denom += __shfl_xor(denom, 16, 64);
    denom += __shfl_xor(denom, 32, 64);

    float inv = 1.0f / denom;
    float v0 = acc[0] * inv, v1 = acc[1] * inv, v2 = acc[2] * inv, v3 = acc[3] * inv;
    // log_softmax over the 64 values (identical in all 4 groups; reduce within group)
    float mx = fmaxf(fmaxf(v0, v1), fmaxf(v2, v3));
#pragma unroll
    for (int m = 8; m > 0; m >>= 1) mx = fmaxf(mx, __shfl_xor(mx, m, 64));
    float se = __expf(v0 - mx) + __expf(v1 - mx) + __expf(v2 - mx) + __expf(v3 - mx);
#pragma unroll
    for (int m = 8; m > 0; m >>= 1) se += __shfl_xor(se, m, 64);
    float lse = mx + logf(se);
    if (g == 0) {
        float* op = OUT + (size_t)node * 64 + t * 4;
        *reinterpret_cast<float4*>(op) = make_float4(v0 - lse, v1 - lse, v2 - lse, v3 - lse);
    }
}

extern "C" void kernel_launch(void* const* d_in, const int* in_sizes, int n_in,
                              void* d_out, int out_size, void* d_ws, size_t ws_size,
                              hipStream_t stream)
{
    const float* x  = (const float*)d_in[0];
    const int*   ei = (const int*)d_in[1];
    const float* W1 = (const float*)d_in[2];
    const float* b1 = (const float*)d_in[3];
    const float* W2 = (const float*)d_in[4];
    const float* b2 = (const float*)d_in[5];
    const float* W3 = (const float*)d_in[6];
    const float* b3 = (const float*)d_in[7];
    float* out = (float*)d_out;

    const int n = in_sizes[0] / 128;
    const int e = in_sizes[1] / 2;
    const int* esrc = ei;
    const int* edst = ei + e;

    char* w = (char*)d_ws;
    float* h    = (float*)w;  w += (size_t)n * 128 * sizeof(float);
    float* conv = (float*)w;  w += (size_t)n * 128 * sizeof(float);
    float* rinv = (float*)w;  w += (size_t)n * sizeof(float);
    float* exs  = (float*)w;  w += (size_t)n * sizeof(float);
    int* rowst  = (int*)w;    w += (size_t)(n + 1) * sizeof(int);
    int* cursor = (int*)w;    w += (size_t)n * sizeof(int);
    int* deg    = (int*)w;    w += (size_t)n * sizeof(int);
    int* incl   = (int*)w;    w += (size_t)n * sizeof(int);
    int* bsum   = (int*)w;    w += 64 * sizeof(int);
    int* csrc   = (int*)w;    w += (size_t)e * sizeof(int);
    short* w1h  = (short*)w;  w += 128 * 128 * sizeof(short);
    short* w1l  = (short*)w;  w += 128 * 128 * sizeof(short);
    short* w2h  = (short*)w;  w += 128 * 128 * sizeof(short);
    short* w2l  = (short*)w;  w += 128 * 128 * sizeof(short);
    short* w3h  = (short*)w;  w += 64 * 128 * sizeof(short);
    short* w3l  = (short*)w;  w += 64 * 128 * sizeof(short);

    const int nb = (n + 1023) / 1024;

    hipMemsetAsync(deg, 0, (size_t)n * sizeof(int), stream);
    k_hist<<<(e + 255) / 256, 256, 0, stream>>>(edst, deg, e);
    k_wsplit<<<64, 256, 0, stream>>>(W1, w1h, w1l, 128 * 128);
    k_wsplit<<<64, 256, 0, stream>>>(W2, w2h, w2l, 128 * 128);
    k_wsplit<<<32, 256, 0, stream>>>(W3, w3h, w3l, 64 * 128);
    k_scan_blk<<<nb, 1024, 0, stream>>>(deg, incl, bsum, n);
    k_scan_top<<<1, 64, 0, stream>>>(bsum, nb);
    k_scan_fin<<<nb, 1024, 0, stream>>>(deg, incl, bsum, rowst, cursor, n);
    k_fill<<<(e + 255) / 256, 256, 0, stream>>>(esrc, edst, cursor, csrc, e);

    const int nwv = (n + 15) / 16;
    const int lgrid = (nwv + 3) / 4;
    const int agrid = (n + 3) / 4;

    k_linear_mfma<128, false><<<lgrid, 256, 0, stream>>>(x, w1h, w1l, b1, h, rinv, exs, n);
    k_agg128<<<agrid, 256, 0, stream>>>(h, rinv, exs, rowst, csrc, conv, n);
    k_linear_mfma<128, true><<<lgrid, 256, 0, stream>>>(conv, w2h, w2l, b2, h, rinv, exs, n);
    k_agg128<<<agrid, 256, 0, stream>>>(h, rinv, exs, rowst, csrc, conv, n);
    k_linear_mfma<64, true><<<lgrid, 256, 0, stream>>>(conv, w3h, w3l, b3, h, rinv, exs, n);
    k_agg64_lsm<<<agrid, 256, 0, stream>>>(h, rinv, exs, rowst, csrc, out, n);
}

// Round 6
// 321.882 us; speedup vs baseline: 4.1198x; 1.1278x over previous
//
#include <hip/hip_runtime.h>

typedef float f32x4 __attribute__((ext_vector_type(4)));
typedef short bf16x8 __attribute__((ext_vector_type(8)));
typedef _Float16 half2_t __attribute__((ext_vector_type(2)));
typedef _Float16 half4_t __attribute__((ext_vector_type(4)));
typedef _Float16 half8_t __attribute__((ext_vector_type(8)));

__device__ __forceinline__ unsigned short bf16_rne(float x) {
    unsigned u = __float_as_uint(x);
    unsigned r = (u + 0x7FFFu + ((u >> 16) & 1u)) >> 16;
    return (unsigned short)r;
}

// ---------------- CSR build (by dst) ----------------
__global__ void k_hist(const int* __restrict__ dst, int* __restrict__ deg, int e) {
    int i = blockIdx.x * blockDim.x + threadIdx.x;
    if (i < e) atomicAdd(&deg[dst[i]], 1);
}

__global__ __launch_bounds__(1024) void k_scan_blk(
    const int* __restrict__ deg, int* __restrict__ incl, int* __restrict__ bsum, int n)
{
    int tid = threadIdx.x, lane = tid & 63, wv = tid >> 6;
    int gid = blockIdx.x * 1024 + tid;
    int x = (gid < n) ? deg[gid] : 0;
    int v = x;
#pragma unroll
    for (int off = 1; off < 64; off <<= 1) {
        int t = __shfl_up(v, off, 64);
        if (lane >= off) v += t;
    }
    __shared__ int wsum[16];
    if (lane == 63) wsum[wv] = v;
    __syncthreads();
    if (wv == 0) {
        int w = (lane < 16) ? wsum[lane] : 0;
#pragma unroll
        for (int off = 1; off < 16; off <<= 1) {
            int t = __shfl_up(w, off, 64);
            if (lane >= off) w += t;
        }
        if (lane < 16) wsum[lane] = w;
    }
    __syncthreads();
    if (wv > 0) v += wsum[wv - 1];
    if (gid < n) incl[gid] = v;
    if (tid == 1023) bsum[blockIdx.x] = v;
}

__global__ void k_scan_top(int* __restrict__ bsum, int nb) {
    int lane = threadIdx.x;
    int v = (lane < nb) ? bsum[lane] : 0;
#pragma unroll
    for (int off = 1; off < 64; off <<= 1) {
        int t = __shfl_up(v, off, 64);
        if (lane >= off) v += t;
    }
    if (lane < nb) bsum[lane] = v;
}

__global__ __launch_bounds__(1024) void k_scan_fin(
    const int* __restrict__ deg, const int* __restrict__ incl, const int* __restrict__ bsum,
    int* __restrict__ rowst, int* __restrict__ cursor, int n)
{
    int gid = blockIdx.x * 1024 + threadIdx.x;
    int boff = (blockIdx.x > 0) ? bsum[blockIdx.x - 1] : 0;
    if (gid < n) {
        int r = boff + incl[gid] - deg[gid];
        rowst[gid] = r;
        cursor[gid] = r;
        if (gid == n - 1) rowst[n] = boff + incl[gid];
    }
}

__global__ void k_fill(const int* __restrict__ src, const int* __restrict__ dst,
                       int* __restrict__ cursor, int* __restrict__ csrc, int e) {
    int i = blockIdx.x * blockDim.x + threadIdx.x;
    if (i < e) {
        int p = atomicAdd(&cursor[dst[i]], 1);
        csrc[p] = src[i];
    }
}

// ---------------- W hi/lo bf16 split ----------------
__global__ void k_wsplit(const float* __restrict__ W, short* __restrict__ hi,
                         short* __restrict__ lo, int count) {
    int i = blockIdx.x * blockDim.x + threadIdx.x;
    if (i < count) {
        float v = W[i];
        unsigned short h = bf16_rne(v);
        float hf = __uint_as_float(((unsigned)h) << 16);
        unsigned short l = bf16_rne(v - hf);
        hi[i] = (short)h;
        lo[i] = (short)l;
    }
}

// ---------------- MFMA Linear -> normalized fp16 features ----------------
// Hn[row] = (X@W^T+b)/||.|| in fp16; nrm = ||.|| fp32; exself = exp(cos_self).
template <int DOUT, bool RELU>
__global__ __launch_bounds__(256) void k_linear_mfma(
    const float* __restrict__ X, const short* __restrict__ Whi, const short* __restrict__ Wlo,
    const float* __restrict__ B, _Float16* __restrict__ Hn,
    float* __restrict__ nrm, float* __restrict__ exself, int n)
{
    constexpr int NT = DOUT / 16;
    const int lane = threadIdx.x & 63;
    const int wid = blockIdx.x * 4 + (threadIdx.x >> 6);
    const int nw = (n + 15) >> 4;
    if (wid >= nw) return;
    const int rg = wid << 4;
    const int r16 = lane & 15, kh = lane >> 4;

    f32x4 acc[NT];
#pragma unroll
    for (int t = 0; t < NT; t++) acc[t] = (f32x4){0.f, 0.f, 0.f, 0.f};

    const float* xp = X + (size_t)(rg + r16) * 128 + kh * 8;

#pragma unroll 1
    for (int ks = 0; ks < 4; ks++) {
        float4 xa = *reinterpret_cast<const float4*>(xp + ks * 32);
        float4 xb = *reinterpret_cast<const float4*>(xp + ks * 32 + 4);
        float xv[8] = {xa.x, xa.y, xa.z, xa.w, xb.x, xb.y, xb.z, xb.w};
        bf16x8 ahi, alo;
#pragma unroll
        for (int j = 0; j < 8; j++) {
            float v = xv[j];
            if (RELU) v = fmaxf(v, 0.f);
            unsigned short h = bf16_rne(v);
            float hf = __uint_as_float(((unsigned)h) << 16);
            unsigned short l = bf16_rne(v - hf);
            ahi[j] = (short)h;
            alo[j] = (short)l;
        }
        const int wo = kh * 8 + ks * 32;
#pragma unroll
        for (int t = 0; t < NT; t++) {
            const short* wh = Whi + (size_t)(t * 16 + r16) * 128 + wo;
            const short* wl = Wlo + (size_t)(t * 16 + r16) * 128 + wo;
            bf16x8 bh = *reinterpret_cast<const bf16x8*>(wh);
            bf16x8 bl = *reinterpret_cast<const bf16x8*>(wl);
            acc[t] = __builtin_amdgcn_mfma_f32_16x16x32_bf16(ahi, bh, acc[t], 0, 0, 0);
            acc[t] = __builtin_amdgcn_mfma_f32_16x16x32_bf16(alo, bh, acc[t], 0, 0, 0);
            acc[t] = __builtin_amdgcn_mfma_f32_16x16x32_bf16(ahi, bl, acc[t], 0, 0, 0);
        }
    }

    float ss[4] = {0.f, 0.f, 0.f, 0.f};
#pragma unroll
    for (int t = 0; t < NT; t++) {
        float bs = B[t * 16 + r16];
#pragma unroll
        for (int r = 0; r < 4; r++) {
            float v = acc[t][r] + bs;
            acc[t][r] = v;
            ss[r] += v * v;
        }
    }
#pragma unroll
    for (int m = 8; m > 0; m >>= 1) {
#pragma unroll
        for (int r = 0; r < 4; r++) ss[r] += __shfl_xor(ss[r], m, 64);
    }
    float nrmv[4], riv[4];
#pragma unroll
    for (int r = 0; r < 4; r++) {
        nrmv[r] = sqrtf(ss[r]);
        riv[r] = 1.0f / fmaxf(nrmv[r], 1e-12f);
    }
#pragma unroll
    for (int t = 0; t < NT; t++) {
#pragma unroll
        for (int r = 0; r < 4; r++) {
            int grow = rg + kh * 4 + r;
            if (grow < n)
                Hn[(size_t)grow * DOUT + t * 16 + r16] = (_Float16)(acc[t][r] * riv[r]);
        }
    }
    if (r16 == 0) {
#pragma unroll
        for (int r = 0; r < 4; r++) {
            int grow = rg + kh * 4 + r;
            if (grow < n) {
                float s = nrmv[r] * riv[r];
                nrm[grow] = nrmv[r];
                exself[grow] = __expf(s * s);
            }
        }
    }
}

// ---------------- Fused attention aggregation (fp16 normalized rows) ----------------
// out[i] = (es*nrm_i*hn_i + sum_e exp(hn_i.hn_s)*nrm_s*hn_s) / (es + sum_e exp(..))
// 16-lane groups x 4 edge slots; lane holds 8 dims (16 B -> one dwordx4 gather).
__global__ __launch_bounds__(256) void k_agg128(
    const _Float16* __restrict__ Hn, const float* __restrict__ nrm, const float* __restrict__ exself,
    const int* __restrict__ rowst, const int* __restrict__ csrc,
    float* __restrict__ OUT, int n)
{
    const int wave = threadIdx.x >> 6, lane = threadIdx.x & 63;
    const int node = blockIdx.x * 4 + wave;
    if (node >= n) return;
    const int g = lane >> 4;
    const int t = lane & 15;

    half8_t hv = *reinterpret_cast<const half8_t*>(Hn + (size_t)node * 128 + t * 8);
    half2_t h2[4];
#pragma unroll
    for (int j = 0; j < 4; j++) h2[j] = (half2_t){hv[2 * j], hv[2 * j + 1]};
    float es = exself[node];
    float esn = es * nrm[node];
    float acc[8];
    float denom;
    if (g == 0) {
#pragma unroll
        for (int j = 0; j < 8; j++) acc[j] = esn * (float)hv[j];
        denom = es;
    } else {
#pragma unroll
        for (int j = 0; j < 8; j++) acc[j] = 0.f;
        denom = 0.f;
    }

    const int p0 = rowst[node], p1 = rowst[node + 1];
    const int iters = (p1 - p0 + 3) >> 2;
    int it = 0;
    for (; it + 2 <= iters; it += 2) {
        int pA = p0 + it * 4 + g, pB = pA + 4;
        bool vA = pA < p1, vB = pB < p1;
        int sA = vA ? csrc[pA] : node;
        int sB = vB ? csrc[pB] : node;
        half8_t av = *reinterpret_cast<const half8_t*>(Hn + (size_t)sA * 128 + t * 8);
        half8_t bv = *reinterpret_cast<const half8_t*>(Hn + (size_t)sB * 128 + t * 8);
        float nA = nrm[sA], nB = nrm[sB];
        half2_t da2 = (half2_t){hv[0], hv[1]} * (half2_t){av[0], av[1]};
        half2_t db2 = (half2_t){hv[0], hv[1]} * (half2_t){bv[0], bv[1]};
#pragma unroll
        for (int j = 1; j < 4; j++) {
            da2 += h2[j] * (half2_t){av[2 * j], av[2 * j + 1]};
            db2 += h2[j] * (half2_t){bv[2 * j], bv[2 * j + 1]};
        }
        float dA = (float)da2[0] + (float)da2[1];
        float dB = (float)db2[0] + (float)db2[1];
#pragma unroll
        for (int m = 8; m > 0; m >>= 1) {
            dA += __shfl_xor(dA, m, 64);
            dB += __shfl_xor(dB, m, 64);
        }
        float exA = vA ? __expf(dA) : 0.f;
        float exB = vB ? __expf(dB) : 0.f;
        denom += exA + exB;
        float wA = exA * nA, wB = exB * nB;
#pragma unroll
        for (int j = 0; j < 8; j++) acc[j] += wA * (float)av[j] + wB * (float)bv[j];
    }
    for (; it < iters; it++) {
        int pA = p0 + it * 4 + g;
        bool vA = pA < p1;
        int sA = vA ? csrc[pA] : node;
        half8_t av = *reinterpret_cast<const half8_t*>(Hn + (size_t)sA * 128 + t * 8);
        float nA = nrm[sA];
        half2_t da2 = (half2_t){hv[0], hv[1]} * (half2_t){av[0], av[1]};
#pragma unroll
        for (int j = 1; j < 4; j++) da2 += h2[j] * (half2_t){av[2 * j], av[2 * j + 1]};
        float dA = (float)da2[0] + (float)da2[1];
#pragma unroll
        for (int m = 8; m > 0; m >>= 1) dA += __shfl_xor(dA, m, 64);
        float exA = vA ? __expf(dA) : 0.f;
        denom += exA;
        float wA = exA * nA;
#pragma unroll
        for (int j = 0; j < 8; j++) acc[j] += wA * (float)av[j];
    }

#pragma unroll
    for (int j = 0; j < 8; j++) {
        acc[j] += __shfl_xor(acc[j], 16, 64);
        acc[j] += __shfl_xor(acc[j], 32, 64);
    }
    denom += __shfl_xor(denom, 16, 64);
    denom += __shfl_xor(denom, 32, 64);

    if (g == 0) {
        float inv = 1.0f / denom;
        float4 o0 = make_float4(acc[0] * inv, acc[1] * inv, acc[2] * inv, acc[3] * inv);
        float4 o1 = make_float4(acc[4] * inv, acc[5] * inv, acc[6] * inv, acc[7] * inv);
        float* op = OUT + (size_t)node * 128 + t * 8;
        *reinterpret_cast<float4*>(op) = o0;
        *reinterpret_cast<float4*>(op + 4) = o1;
    }
}

// D=64: 16-lane groups, 4 dims/lane, fused log_softmax epilogue
__global__ __launch_bounds__(256) void k_agg64_lsm(
    const _Float16* __restrict__ Hn, const float* __restrict__ nrm, const float* __restrict__ exself,
    const int* __restrict__ rowst, const int* __restrict__ csrc,
    float* __restrict__ OUT, int n)
{
    const int wave = threadIdx.x >> 6, lane = threadIdx.x & 63;
    const int node = blockIdx.x * 4 + wave;
    if (node >= n) return;
    const int g = lane >> 4;
    const int t = lane & 15;

    half4_t hv = *reinterpret_cast<const half4_t*>(Hn + (size_t)node * 64 + t * 4);
    half2_t h2[2] = {(half2_t){hv[0], hv[1]}, (half2_t){hv[2], hv[3]}};
    float es = exself[node];
    float esn = es * nrm[node];
    float acc[4];
    float denom;
    if (g == 0) {
#pragma unroll
        for (int j = 0; j < 4; j++) acc[j] = esn * (float)hv[j];
        denom = es;
    } else {
        acc[0] = acc[1] = acc[2] = acc[3] = 0.f;
        denom = 0.f;
    }

    const int p0 = rowst[node], p1 = rowst[node + 1];
    const int iters = (p1 - p0 + 3) >> 2;
    int it = 0;
    for (; it + 2 <= iters; it += 2) {
        int pA = p0 + it * 4 + g, pB = pA + 4;
        bool vA = pA < p1, vB = pB < p1;
        int sA = vA ? csrc[pA] : node;
        int sB = vB ? csrc[pB] : node;
        half4_t av = *reinterpret_cast<const half4_t*>(Hn + (size_t)sA * 64 + t * 4);
        half4_t bv = *reinterpret_cast<const half4_t*>(Hn + (size_t)sB * 64 + t * 4);
        float nA = nrm[sA], nB = nrm[sB];
        half2_t da2 = h2[0] * (half2_t){av[0], av[1]} ;
        half2_t db2 = h2[0] * (half2_t){bv[0], bv[1]};
        da2 += h2[1] * (half2_t){av[2], av[3]};
        db2 += h2[1] * (half2_t){bv[2], bv[3]};
        float dA = (float)da2[0] + (float)da2[1];
        float dB = (float)db2[0] + (float)db2[1];
#pragma unroll
        for (int m = 8; m > 0; m >>= 1) {
            dA += __shfl_xor(dA, m, 64);
            dB += __shfl_xor(dB, m, 64);
        }
        float exA = vA ? __expf(dA) : 0.f;
        float exB = vB ? __expf(dB) : 0.f;
        denom += exA + exB;
        float wA = exA * nA, wB = exB * nB;
#pragma unroll
        for (int j = 0; j < 4; j++) acc[j] += wA * (float)av[j] + wB * (float)bv[j];
    }
    for (; it < iters; it++) {
        int pA = p0 + it * 4 + g;
        bool vA = pA < p1;
        int sA = vA ? csrc[pA] : node;
        half4_t av = *reinterpret_cast<const half4_t*>(Hn + (size_t)sA * 64 + t * 4);
        float nA = nrm[sA];
        half2_t da2 = h2[0] * (half2_t){av[0], av[1]};
        da2 += h2[1] * (half2_t){av[2], av[3]};
        float dA = (float)da2[0] + (float)da2[1];
#pragma unroll
        for (int m = 8; m > 0; m >>= 1) dA += __shfl_xor(dA, m, 64);
        float exA = vA ? __expf(dA) : 0.f;
        denom += exA;
        float wA = exA * nA;
#pragma unroll
        for (int j = 0; j < 4; j++) acc[j] += wA * (float)av[j];
    }

#pragma unroll
    for (int j = 0; j < 4; j++) {
        acc[j] += __shfl_xor(acc[j], 16, 64);
        acc[j] += __shfl_xor(acc[j], 32, 64);
    }
    denom += __shfl_xor(denom, 16, 64);
    denom += __shfl_xor(denom, 32, 64);

    float inv = 1.0f / denom;
    float v0 = acc[0] * inv, v1 = acc[1] * inv, v2 = acc[2] * inv, v3 = acc[3] * inv;
    float mx = fmaxf(fmaxf(v0, v1), fmaxf(v2, v3));
#pragma unroll
    for (int m = 8; m > 0; m >>= 1) mx = fmaxf(mx, __shfl_xor(mx, m, 64));
    float se = __expf(v0 - mx) + __expf(v1 - mx) + __expf(v2 - mx) + __expf(v3 - mx);
#pragma unroll
    for (int m = 8; m > 0; m >>= 1) se += __shfl_xor(se, m, 64);
    float lse = mx + logf(se);
    if (g == 0) {
        float* op = OUT + (size_t)node * 64 + t * 4;
        *reinterpret_cast<float4*>(op) = make_float4(v0 - lse, v1 - lse, v2 - lse, v3 - lse);
    }
}

extern "C" void kernel_launch(void* const* d_in, const int* in_sizes, int n_in,
                              void* d_out, int out_size, void* d_ws, size_t ws_size,
                              hipStream_t stream)
{
    const float* x  = (const float*)d_in[0];
    const int*   ei = (const int*)d_in[1];
    const float* W1 = (const float*)d_in[2];
    const float* b1 = (const float*)d_in[3];
    const float* W2 = (const float*)d_in[4];
    const float* b2 = (const float*)d_in[5];
    const float* W3 = (const float*)d_in[6];
    const float* b3 = (const float*)d_in[7];
    float* out = (float*)d_out;

    const int n = in_sizes[0] / 128;
    const int e = in_sizes[1] / 2;
    const int* esrc = ei;
    const int* edst = ei + e;

    char* w = (char*)d_ws;
    float* conv     = (float*)w;     w += (size_t)n * 128 * sizeof(float);
    _Float16* hn16  = (_Float16*)w; w += (size_t)n * 128 * sizeof(_Float16);
    float* nrm  = (float*)w;  w += (size_t)n * sizeof(float);
    float* exs  = (float*)w;  w += (size_t)n * sizeof(float);
    int* rowst  = (int*)w;    w += (size_t)(n + 1) * sizeof(int);
    int* cursor = (int*)w;    w += (size_t)n * sizeof(int);
    int* deg    = (int*)w;    w += (size_t)n * sizeof(int);
    int* incl   = (int*)w;    w += (size_t)n * sizeof(int);
    int* bsum   = (int*)w;    w += 64 * sizeof(int);
    int* csrc   = (int*)w;    w += (size_t)e * sizeof(int);
    short* w1h  = (short*)w;  w += 128 * 128 * sizeof(short);
    short* w1l  = (short*)w;  w += 128 * 128 * sizeof(short);
    short* w2h  = (short*)w;  w += 128 * 128 * sizeof(short);
    short* w2l  = (short*)w;  w += 128 * 128 * sizeof(short);
    short* w3h  = (short*)w;  w += 64 * 128 * sizeof(short);
    short* w3l  = (short*)w;  w += 64 * 128 * sizeof(short);

    const int nb = (n + 1023) / 1024;

    hipMemsetAsync(deg, 0, (size_t)n * sizeof(int), stream);
    k_hist<<<(e + 255) / 256, 256, 0, stream>>>(edst, deg, e);
    k_wsplit<<<64, 256, 0, stream>>>(W1, w1h, w1l, 128 * 128);
    k_wsplit<<<64, 256, 0, stream>>>(W2, w2h, w2l, 128 * 128);
    k_wsplit<<<32, 256, 0, stream>>>(W3, w3h, w3l, 64 * 128);
    k_scan_blk<<<nb, 1024, 0, stream>>>(deg, incl, bsum, n);
    k_scan_top<<<1, 64, 0, stream>>>(bsum, nb);
    k_scan_fin<<<nb, 1024, 0, stream>>>(deg, incl, bsum, rowst, cursor, n);
    k_fill<<<(e + 255) / 256, 256, 0, stream>>>(esrc, edst, cursor, csrc, e);

    const int nwv = (n + 15) / 16;
    const int lgrid = (nwv + 3) / 4;
    const int agrid = (n + 3) / 4;

    k_linear_mfma<128, false><<<lgrid, 256, 0, stream>>>(x, w1h, w1l, b1, hn16, nrm, exs, n);
    k_agg128<<<agrid, 256, 0, stream>>>(hn16, nrm, exs, rowst, csrc, conv, n);
    k_linear_mfma<128, true><<<lgrid, 256, 0, stream>>>(conv, w2h, w2l, b2, hn16, nrm, exs, n);
    k_agg128<<<agrid, 256, 0, stream>>>(hn16, nrm, exs, rowst, csrc, conv, n);
    k_linear_mfma<64, true><<<lgrid, 256, 0, stream>>>(conv, w3h, w3l, b3, hn16, nrm, exs, n);
    k_agg64_lsm<<<agrid, 256, 0, stream>>>(hn16, nrm, exs, rowst, csrc, out, n);
}

// Round 7
// 259.444 us; speedup vs baseline: 5.1113x; 1.2407x over previous
//
#include <hip/hip_runtime.h>

typedef float f32x4 __attribute__((ext_vector_type(4)));
typedef short bf16x8 __attribute__((ext_vector_type(8)));
typedef _Float16 half2_t __attribute__((ext_vector_type(2)));
typedef _Float16 half4_t __attribute__((ext_vector_type(4)));
typedef _Float16 half8_t __attribute__((ext_vector_type(8)));

__device__ __forceinline__ unsigned short bf16_rne(float x) {
    unsigned u = __float_as_uint(x);
    unsigned r = (u + 0x7FFFu + ((u >> 16) & 1u)) >> 16;
    return (unsigned short)r;
}

// ================= CSR build via 2-level counting sort =================
// Edges packed as (dst<<16)|src  (requires n <= 65536; here n = 50000).
// Coarse bin = dst>>7 (128 dsts/bin). Eliminates the atomic-scatter fill
// whose 4B writes caused 1 full 64B HBM writeback per edge (R6: 51 MB).
#define CSR_CHUNK 4096

__global__ __launch_bounds__(256) void k_bh(const int* __restrict__ dst,
                                            int* __restrict__ gh, int e, int nbin) {
    __shared__ int lh[512];
    for (int i = threadIdx.x; i < nbin; i += 256) lh[i] = 0;
    __syncthreads();
    int lo = blockIdx.x * CSR_CHUNK;
    int hi = min(lo + CSR_CHUNK, e);
    for (int i = lo + threadIdx.x; i < hi; i += 256)
        atomicAdd(&lh[dst[i] >> 7], 1);
    __syncthreads();
    for (int i = threadIdx.x; i < nbin; i += 256)
        if (lh[i]) atomicAdd(&gh[i], lh[i]);
}

// exclusive scan of gh[0..nbin) (nbin <= 512), one block of 512
__global__ __launch_bounds__(512) void k_bscan(
    const int* __restrict__ gh, int* __restrict__ binstart, int* __restrict__ bincur,
    int* __restrict__ rowst, int e, int nbin, int n)
{
    int tid = threadIdx.x, lane = tid & 63, wv = tid >> 6;
    __shared__ int ws[8];
    int x = (tid < nbin) ? gh[tid] : 0;
    int v = x;
#pragma unroll
    for (int off = 1; off < 64; off <<= 1) {
        int t = __shfl_up(v, off, 64);
        if (lane >= off) v += t;
    }
    if (lane == 63) ws[wv] = v;
    __syncthreads();
    if (wv == 0) {
        int w = (lane < 8) ? ws[lane] : 0;
#pragma unroll
        for (int off = 1; off < 8; off <<= 1) {
            int t = __shfl_up(w, off, 64);
            if (lane >= off) w += t;
        }
        if (lane < 8) ws[lane] = w;
    }
    __syncthreads();
    if (wv > 0) v += ws[wv - 1];
    int excl = v - x;
    if (tid < nbin) { binstart[tid] = excl; bincur[tid] = excl; }
    if (tid == 0) { binstart[nbin] = e; rowst[n] = e; }
}

__global__ __launch_bounds__(256) void k_scatter(
    const int* __restrict__ src, const int* __restrict__ dst,
    int* __restrict__ bincur, unsigned* __restrict__ sorted, int e, int nbin)
{
    __shared__ unsigned st[CSR_CHUNK];
    __shared__ int lh[512];
    __shared__ int base[512];
    for (int i = threadIdx.x; i < nbin; i += 256) lh[i] = 0;
    __syncthreads();
    int lo = blockIdx.x * CSR_CHUNK;
    int cnt = min(lo + CSR_CHUNK, e) - lo;
    for (int i = threadIdx.x; i < cnt; i += 256) {
        int d = dst[lo + i], s = src[lo + i];
        st[i] = ((unsigned)d << 16) | (unsigned)s;
        atomicAdd(&lh[d >> 7], 1);
    }
    __syncthreads();
    for (int i = threadIdx.x; i < nbin; i += 256) {
        int c = lh[i];
        base[i] = c ? atomicAdd(&bincur[i], c) : 0;
        lh[i] = 0;                       // reuse as within-block cursor
    }
    __syncthreads();
    for (int i = threadIdx.x; i < cnt; i += 256) {
        unsigned u = st[i];
        int b = (int)(u >> 23);          // dst >> 7
        int r = atomicAdd(&lh[b], 1);
        sorted[base[b] + r] = u;
    }
}

// one block per coarse bin: fine 128-dst counting sort; emits rowst + csrc
__global__ __launch_bounds__(256) void k_fine(
    const unsigned* __restrict__ sorted, const int* __restrict__ binstart,
    int* __restrict__ rowst, int* __restrict__ csrc, int n)
{
    int b = blockIdx.x;
    int s = binstart[b], t = binstart[b + 1];
    __shared__ int fh[128], fex[128], fcur[128];
    __shared__ int wtot;
    int tid = threadIdx.x;
    if (tid < 128) fh[tid] = 0;
    __syncthreads();
    for (int i = s + tid; i < t; i += 256)
        atomicAdd(&fh[(sorted[i] >> 16) & 127], 1);
    __syncthreads();
    if (tid < 128) {
        int lane = tid & 63;
        int x = fh[tid];
        int v = x;
#pragma unroll
        for (int off = 1; off < 64; off <<= 1) {
            int tv = __shfl_up(v, off, 64);
            if (lane >= off) v += tv;
        }
        fex[tid] = v - x;
        if (tid == 63) wtot = v;
    }
    __syncthreads();
    if (tid >= 64 && tid < 128) fex[tid] += wtot;
    __syncthreads();
    if (tid < 128) {
        int node = b * 128 + tid;
        if (node < n) rowst[node] = s + fex[tid];
        fcur[tid] = 0;
    }
    __syncthreads();
    for (int i = s + tid; i < t; i += 256) {
        unsigned u = sorted[i];
        int d = (u >> 16) & 127;
        int r = atomicAdd(&fcur[d], 1);
        csrc[s + fex[d] + r] = (int)(u & 0xFFFFu);
    }
}

// ---------------- W hi/lo bf16 split ----------------
__global__ void k_wsplit(const float* __restrict__ W, short* __restrict__ hi,
                         short* __restrict__ lo, int count) {
    int i = blockIdx.x * blockDim.x + threadIdx.x;
    if (i < count) {
        float v = W[i];
        unsigned short h = bf16_rne(v);
        float hf = __uint_as_float(((unsigned)h) << 16);
        unsigned short l = bf16_rne(v - hf);
        hi[i] = (short)h;
        lo[i] = (short)l;
    }
}

// ---------------- MFMA Linear -> normalized fp16 features ----------------
template <int DOUT, bool RELU>
__global__ __launch_bounds__(256) void k_linear_mfma(
    const float* __restrict__ X, const short* __restrict__ Whi, const short* __restrict__ Wlo,
    const float* __restrict__ B, _Float16* __restrict__ Hn,
    float* __restrict__ nrm, float* __restrict__ exself, int n)
{
    constexpr int NT = DOUT / 16;
    const int lane = threadIdx.x & 63;
    const int wid = blockIdx.x * 4 + (threadIdx.x >> 6);
    const int nw = (n + 15) >> 4;
    if (wid >= nw) return;
    const int rg = wid << 4;
    const int r16 = lane & 15, kh = lane >> 4;

    f32x4 acc[NT];
#pragma unroll
    for (int t = 0; t < NT; t++) acc[t] = (f32x4){0.f, 0.f, 0.f, 0.f};

    const float* xp = X + (size_t)(rg + r16) * 128 + kh * 8;

#pragma unroll 1
    for (int ks = 0; ks < 4; ks++) {
        float4 xa = *reinterpret_cast<const float4*>(xp + ks * 32);
        float4 xb = *reinterpret_cast<const float4*>(xp + ks * 32 + 4);
        float xv[8] = {xa.x, xa.y, xa.z, xa.w, xb.x, xb.y, xb.z, xb.w};
        bf16x8 ahi, alo;
#pragma unroll
        for (int j = 0; j < 8; j++) {
            float v = xv[j];
            if (RELU) v = fmaxf(v, 0.f);
            unsigned short h = bf16_rne(v);
            float hf = __uint_as_float(((unsigned)h) << 16);
            unsigned short l = bf16_rne(v - hf);
            ahi[j] = (short)h;
            alo[j] = (short)l;
        }
        const int wo = kh * 8 + ks * 32;
#pragma unroll
        for (int t = 0; t < NT; t++) {
            const short* wh = Whi + (size_t)(t * 16 + r16) * 128 + wo;
            const short* wl = Wlo + (size_t)(t * 16 + r16) * 128 + wo;
            bf16x8 bh = *reinterpret_cast<const bf16x8*>(wh);
            bf16x8 bl = *reinterpret_cast<const bf16x8*>(wl);
            acc[t] = __builtin_amdgcn_mfma_f32_16x16x32_bf16(ahi, bh, acc[t], 0, 0, 0);
            acc[t] = __builtin_amdgcn_mfma_f32_16x16x32_bf16(alo, bh, acc[t], 0, 0, 0);
            acc[t] = __builtin_amdgcn_mfma_f32_16x16x32_bf16(ahi, bl, acc[t], 0, 0, 0);
        }
    }

    float ss[4] = {0.f, 0.f, 0.f, 0.f};
#pragma unroll
    for (int t = 0; t < NT; t++) {
        float bs = B[t * 16 + r16];
#pragma unroll
        for (int r = 0; r < 4; r++) {
            float v = acc[t][r] + bs;
            acc[t][r] = v;
            ss[r] += v * v;
        }
    }
#pragma unroll
    for (int m = 8; m > 0; m >>= 1) {
#pragma unroll
        for (int r = 0; r < 4; r++) ss[r] += __shfl_xor(ss[r], m, 64);
    }
    float nrmv[4], riv[4];
#pragma unroll
    for (int r = 0; r < 4; r++) {
        nrmv[r] = sqrtf(ss[r]);
        riv[r] = 1.0f / fmaxf(nrmv[r], 1e-12f);
    }
#pragma unroll
    for (int t = 0; t < NT; t++) {
#pragma unroll
        for (int r = 0; r < 4; r++) {
            int grow = rg + kh * 4 + r;
            if (grow < n)
                Hn[(size_t)grow * DOUT + t * 16 + r16] = (_Float16)(acc[t][r] * riv[r]);
        }
    }
    if (r16 == 0) {
#pragma unroll
        for (int r = 0; r < 4; r++) {
            int grow = rg + kh * 4 + r;
            if (grow < n) {
                float s = nrmv[r] * riv[r];
                nrm[grow] = nrmv[r];
                exself[grow] = __expf(s * s);
            }
        }
    }
}

// ---------------- Fused attention aggregation (fp16 normalized rows) ----------------
__global__ __launch_bounds__(256) void k_agg128(
    const _Float16* __restrict__ Hn, const float* __restrict__ nrm, const float* __restrict__ exself,
    const int* __restrict__ rowst, const int* __restrict__ csrc,
    float* __restrict__ OUT, int n)
{
    const int wave = threadIdx.x >> 6, lane = threadIdx.x & 63;
    const int node = blockIdx.x * 4 + wave;
    if (node >= n) return;
    const int g = lane >> 4;
    const int t = lane & 15;

    half8_t hv = *reinterpret_cast<const half8_t*>(Hn + (size_t)node * 128 + t * 8);
    half2_t h2[4];
#pragma unroll
    for (int j = 0; j < 4; j++) h2[j] = (half2_t){hv[2 * j], hv[2 * j + 1]};
    float es = exself[node];
    float esn = es * nrm[node];
    float acc[8];
    float denom;
    if (g == 0) {
#pragma unroll
        for (int j = 0; j < 8; j++) acc[j] = esn * (float)hv[j];
        denom = es;
    } else {
#pragma unroll
        for (int j = 0; j < 8; j++) acc[j] = 0.f;
        denom = 0.f;
    }

    const int p0 = rowst[node], p1 = rowst[node + 1];
    const int iters = (p1 - p0 + 3) >> 2;
    int it = 0;
    for (; it + 2 <= iters; it += 2) {
        int pA = p0 + it * 4 + g, pB = pA + 4;
        bool vA = pA < p1, vB = pB < p1;
        int sA = vA ? csrc[pA] : node;
        int sB = vB ? csrc[pB] : node;
        half8_t av = *reinterpret_cast<const half8_t*>(Hn + (size_t)sA * 128 + t * 8);
        half8_t bv = *reinterpret_cast<const half8_t*>(Hn + (size_t)sB * 128 + t * 8);
        float nA = nrm[sA], nB = nrm[sB];
        half2_t da2 = (half2_t){hv[0], hv[1]} * (half2_t){av[0], av[1]};
        half2_t db2 = (half2_t){hv[0], hv[1]} * (half2_t){bv[0], bv[1]};
#pragma unroll
        for (int j = 1; j < 4; j++) {
            da2 += h2[j] * (half2_t){av[2 * j], av[2 * j + 1]};
            db2 += h2[j] * (half2_t){bv[2 * j], bv[2 * j + 1]};
        }
        float dA = (float)da2[0] + (float)da2[1];
        float dB = (float)db2[0] + (float)db2[1];
#pragma unroll
        for (int m = 8; m > 0; m >>= 1) {
            dA += __shfl_xor(dA, m, 64);
            dB += __shfl_xor(dB, m, 64);
        }
        float exA = vA ? __expf(dA) : 0.f;
        float exB = vB ? __expf(dB) : 0.f;
        denom += exA + exB;
        float wA = exA * nA, wB = exB * nB;
#pragma unroll
        for (int j = 0; j < 8; j++) acc[j] += wA * (float)av[j] + wB * (float)bv[j];
    }
    for (; it < iters; it++) {
        int pA = p0 + it * 4 + g;
        bool vA = pA < p1;
        int sA = vA ? csrc[pA] : node;
        half8_t av = *reinterpret_cast<const half8_t*>(Hn + (size_t)sA * 128 + t * 8);
        float nA = nrm[sA];
        half2_t da2 = (half2_t){hv[0], hv[1]} * (half2_t){av[0], av[1]};
#pragma unroll
        for (int j = 1; j < 4; j++) da2 += h2[j] * (half2_t){av[2 * j], av[2 * j + 1]};
        float dA = (float)da2[0] + (float)da2[1];
#pragma unroll
        for (int m = 8; m > 0; m >>= 1) dA += __shfl_xor(dA, m, 64);
        float exA = vA ? __expf(dA) : 0.f;
        denom += exA;
        float wA = exA * nA;
#pragma unroll
        for (int j = 0; j < 8; j++) acc[j] += wA * (float)av[j];
    }

#pragma unroll
    for (int j = 0; j < 8; j++) {
        acc[j] += __shfl_xor(acc[j], 16, 64);
        acc[j] += __shfl_xor(acc[j], 32, 64);
    }
    denom += __shfl_xor(denom, 16, 64);
    denom += __shfl_xor(denom, 32, 64);

    if (g == 0) {
        float inv = 1.0f / denom;
        float4 o0 = make_float4(acc[0] * inv, acc[1] * inv, acc[2] * inv, acc[3] * inv);
        float4 o1 = make_float4(acc[4] * inv, acc[5] * inv, acc[6] * inv, acc[7] * inv);
        float* op = OUT + (size_t)node * 128 + t * 8;
        *reinterpret_cast<float4*>(op) = o0;
        *reinterpret_cast<float4*>(op + 4) = o1;
    }
}

__global__ __launch_bounds__(256) void k_agg64_lsm(
    const _Float16* __restrict__ Hn, const float* __restrict__ nrm, const float* __restrict__ exself,
    const int* __restrict__ rowst, const int* __restrict__ csrc,
    float* __restrict__ OUT, int n)
{
    const int wave = threadIdx.x >> 6, lane = threadIdx.x & 63;
    const int node = blockIdx.x * 4 + wave;
    if (node >= n) return;
    const int g = lane >> 4;
    const int t = lane & 15;

    half4_t hv = *reinterpret_cast<const half4_t*>(Hn + (size_t)node * 64 + t * 4);
    half2_t h2[2] = {(half2_t){hv[0], hv[1]}, (half2_t){hv[2], hv[3]}};
    float es = exself[node];
    float esn = es * nrm[node];
    float acc[4];
    float denom;
    if (g == 0) {
#pragma unroll
        for (int j = 0; j < 4; j++) acc[j] = esn * (float)hv[j];
        denom = es;
    } else {
        acc[0] = acc[1] = acc[2] = acc[3] = 0.f;
        denom = 0.f;
    }

    const int p0 = rowst[node], p1 = rowst[node + 1];
    const int iters = (p1 - p0 + 3) >> 2;
    int it = 0;
    for (; it + 2 <= iters; it += 2) {
        int pA = p0 + it * 4 + g, pB = pA + 4;
        bool vA = pA < p1, vB = pB < p1;
        int sA = vA ? csrc[pA] : node;
        int sB = vB ? csrc[pB] : node;
        half4_t av = *reinterpret_cast<const half4_t*>(Hn + (size_t)sA * 64 + t * 4);
        half4_t bv = *reinterpret_cast<const half4_t*>(Hn + (size_t)sB * 64 + t * 4);
        float nA = nrm[sA], nB = nrm[sB];
        half2_t da2 = h2[0] * (half2_t){av[0], av[1]};
        half2_t db2 = h2[0] * (half2_t){bv[0], bv[1]};
        da2 += h2[1] * (half2_t){av[2], av[3]};
        db2 += h2[1] * (half2_t){bv[2], bv[3]};
        float dA = (float)da2[0] + (float)da2[1];
        float dB = (float)db2[0] + (float)db2[1];
#pragma unroll
        for (int m = 8; m > 0; m >>= 1) {
            dA += __shfl_xor(dA, m, 64);
            dB += __shfl_xor(dB, m, 64);
        }
        float exA = vA ? __expf(dA) : 0.f;
        float exB = vB ? __expf(dB) : 0.f;
        denom += exA + exB;
        float wA = exA * nA, wB = exB * nB;
#pragma unroll
        for (int j = 0; j < 4; j++) acc[j] += wA * (float)av[j] + wB * (float)bv[j];
    }
    for (; it < iters; it++) {
        int pA = p0 + it * 4 + g;
        bool vA = pA < p1;
        int sA = vA ? csrc[pA] : node;
        half4_t av = *reinterpret_cast<const half4_t*>(Hn + (size_t)sA * 64 + t * 4);
        float nA = nrm[sA];
        half2_t da2 = h2[0] * (half2_t){av[0], av[1]};
        da2 += h2[1] * (half2_t){av[2], av[3]};
        float dA = (float)da2[0] + (float)da2[1];
#pragma unroll
        for (int m = 8; m > 0; m >>= 1) dA += __shfl_xor(dA, m, 64);
        float exA = vA ? __expf(dA) : 0.f;
        denom += exA;
        float wA = exA * nA;
#pragma unroll
        for (int j = 0; j < 4; j++) acc[j] += wA * (float)av[j];
    }

#pragma unroll
    for (int j = 0; j < 4; j++) {
        acc[j] += __shfl_xor(acc[j], 16, 64);
        acc[j] += __shfl_xor(acc[j], 32, 64);
    }
    denom += __shfl_xor(denom, 16, 64);
    denom += __shfl_xor(denom, 32, 64);

    float inv = 1.0f / denom;
    float v0 = acc[0] * inv, v1 = acc[1] * inv, v2 = acc[2] * inv, v3 = acc[3] * inv;
    float mx = fmaxf(fmaxf(v0, v1), fmaxf(v2, v3));
#pragma unroll
    for (int m = 8; m > 0; m >>= 1) mx = fmaxf(mx, __shfl_xor(mx, m, 64));
    float se = __expf(v0 - mx) + __expf(v1 - mx) + __expf(v2 - mx) + __expf(v3 - mx);
#pragma unroll
    for (int m = 8; m > 0; m >>= 1) se += __shfl_xor(se, m, 64);
    float lse = mx + logf(se);
    if (g == 0) {
        float* op = OUT + (size_t)node * 64 + t * 4;
        *reinterpret_cast<float4*>(op) = make_float4(v0 - lse, v1 - lse, v2 - lse, v3 - lse);
    }
}

extern "C" void kernel_launch(void* const* d_in, const int* in_sizes, int n_in,
                              void* d_out, int out_size, void* d_ws, size_t ws_size,
                              hipStream_t stream)
{
    const float* x  = (const float*)d_in[0];
    const int*   ei = (const int*)d_in[1];
    const float* W1 = (const float*)d_in[2];
    const float* b1 = (const float*)d_in[3];
    const float* W2 = (const float*)d_in[4];
    const float* b2 = (const float*)d_in[5];
    const float* W3 = (const float*)d_in[6];
    const float* b3 = (const float*)d_in[7];
    float* out = (float*)d_out;

    const int n = in_sizes[0] / 128;
    const int e = in_sizes[1] / 2;
    const int* esrc = ei;
    const int* edst = ei + e;

    char* w = (char*)d_ws;
    float* conv     = (float*)w;    w += (size_t)n * 128 * sizeof(float);
    _Float16* hn16  = (_Float16*)w; w += (size_t)n * 128 * sizeof(_Float16);
    float* nrm  = (float*)w;  w += (size_t)n * sizeof(float);
    float* exs  = (float*)w;  w += (size_t)n * sizeof(float);
    int* rowst  = (int*)w;    w += (size_t)(n + 1) * sizeof(int);
    int* gh     = (int*)w;    w += 512 * sizeof(int);
    int* binstart = (int*)w;  w += 513 * sizeof(int);
    int* bincur = (int*)w;    w += 512 * sizeof(int);
    unsigned* sorted = (unsigned*)w; w += (size_t)e * sizeof(unsigned);
    int* csrc   = (int*)w;    w += (size_t)e * sizeof(int);
    short* w1h  = (short*)w;  w += 128 * 128 * sizeof(short);
    short* w1l  = (short*)w;  w += 128 * 128 * sizeof(short);
    short* w2h  = (short*)w;  w += 128 * 128 * sizeof(short);
    short* w2l  = (short*)w;  w += 128 * 128 * sizeof(short);
    short* w3h  = (short*)w;  w += 64 * 128 * sizeof(short);
    short* w3l  = (short*)w;  w += 64 * 128 * sizeof(short);

    const int nbin = (n + 127) >> 7;                 // 391 for n=50000 (<=512)
    const int nchunk = (e + CSR_CHUNK - 1) / CSR_CHUNK;

    // ---- CSR build: 2-level counting sort by dst ----
    hipMemsetAsync(gh, 0, 512 * sizeof(int), stream);
    k_bh<<<nchunk, 256, 0, stream>>>(edst, gh, e, nbin);
    k_bscan<<<1, 512, 0, stream>>>(gh, binstart, bincur, rowst, e, nbin, n);
    k_scatter<<<nchunk, 256, 0, stream>>>(esrc, edst, bincur, sorted, e, nbin);
    k_fine<<<nbin, 256, 0, stream>>>(sorted, binstart, rowst, csrc, n);

    k_wsplit<<<64, 256, 0, stream>>>(W1, w1h, w1l, 128 * 128);
    k_wsplit<<<64, 256, 0, stream>>>(W2, w2h, w2l, 128 * 128);
    k_wsplit<<<32, 256, 0, stream>>>(W3, w3h, w3l, 64 * 128);

    const int nwv = (n + 15) / 16;
    const int lgrid = (nwv + 3) / 4;
    const int agrid = (n + 3) / 4;

    k_linear_mfma<128, false><<<lgrid, 256, 0, stream>>>(x, w1h, w1l, b1, hn16, nrm, exs, n);
    k_agg128<<<agrid, 256, 0, stream>>>(hn16, nrm, exs, rowst, csrc, conv, n);
    k_linear_mfma<128, true><<<lgrid, 256, 0, stream>>>(conv, w2h, w2l, b2, hn16, nrm, exs, n);
    k_agg128<<<agrid, 256, 0, stream>>>(hn16, nrm, exs, rowst, csrc, conv, n);
    k_linear_mfma<64, true><<<lgrid, 256, 0, stream>>>(conv, w3h, w3l, b3, hn16, nrm, exs, n);
    k_agg64_lsm<<<agrid, 256, 0, stream>>>(hn16, nrm, exs, rowst, csrc, out, n);
}

// Round 8
// 220.301 us; speedup vs baseline: 6.0194x; 1.1777x over previous
//
#include <hip/hip_runtime.h>

typedef float f32x4 __attribute__((ext_vector_type(4)));
typedef short bf16x8 __attribute__((ext_vector_type(8)));
typedef _Float16 half2_t __attribute__((ext_vector_type(2)));
typedef _Float16 half4_t __attribute__((ext_vector_type(4)));
typedef _Float16 half8_t __attribute__((ext_vector_type(8)));

__device__ __forceinline__ unsigned short bf16_rne(float x) {
    unsigned u = __float_as_uint(x);
    unsigned r = (u + 0x7FFFu + ((u >> 16) & 1u)) >> 16;
    return (unsigned short)r;
}

// ================= CSR build via 2-level counting sort =================
// Edges packed as (dst<<16)|src (n <= 65536). Coarse bin = dst>>7.
#define CSR_CHUNK 4096

__global__ __launch_bounds__(256) void k_bh(const int* __restrict__ dst,
                                            int* __restrict__ gh, int e, int nbin) {
    __shared__ int lh[512];
    for (int i = threadIdx.x; i < nbin; i += 256) lh[i] = 0;
    __syncthreads();
    int lo = blockIdx.x * CSR_CHUNK;
    int hi = min(lo + CSR_CHUNK, e);
    for (int i = lo + threadIdx.x; i < hi; i += 256)
        atomicAdd(&lh[dst[i] >> 7], 1);
    __syncthreads();
    for (int i = threadIdx.x; i < nbin; i += 256)
        if (lh[i]) atomicAdd(&gh[i], lh[i]);
}

__global__ __launch_bounds__(512) void k_bscan(
    const int* __restrict__ gh, int* __restrict__ binstart, int* __restrict__ bincur,
    int* __restrict__ rowst, int e, int nbin, int n)
{
    int tid = threadIdx.x, lane = tid & 63, wv = tid >> 6;
    __shared__ int ws[8];
    int x = (tid < nbin) ? gh[tid] : 0;
    int v = x;
#pragma unroll
    for (int off = 1; off < 64; off <<= 1) {
        int t = __shfl_up(v, off, 64);
        if (lane >= off) v += t;
    }
    if (lane == 63) ws[wv] = v;
    __syncthreads();
    if (wv == 0) {
        int w = (lane < 8) ? ws[lane] : 0;
#pragma unroll
        for (int off = 1; off < 8; off <<= 1) {
            int t = __shfl_up(w, off, 64);
            if (lane >= off) w += t;
        }
        if (lane < 8) ws[lane] = w;
    }
    __syncthreads();
    if (wv > 0) v += ws[wv - 1];
    int excl = v - x;
    if (tid < nbin) { binstart[tid] = excl; bincur[tid] = excl; }
    if (tid == 0) { binstart[nbin] = e; rowst[n] = e; }
}

__global__ __launch_bounds__(256) void k_scatter(
    const int* __restrict__ src, const int* __restrict__ dst,
    int* __restrict__ bincur, unsigned* __restrict__ sorted, int e, int nbin)
{
    __shared__ unsigned st[CSR_CHUNK];
    __shared__ int lh[512];
    __shared__ int base[512];
    for (int i = threadIdx.x; i < nbin; i += 256) lh[i] = 0;
    __syncthreads();
    int lo = blockIdx.x * CSR_CHUNK;
    int cnt = min(lo + CSR_CHUNK, e) - lo;
    for (int i = threadIdx.x; i < cnt; i += 256) {
        int d = dst[lo + i], s = src[lo + i];
        st[i] = ((unsigned)d << 16) | (unsigned)s;
        atomicAdd(&lh[d >> 7], 1);
    }
    __syncthreads();
    for (int i = threadIdx.x; i < nbin; i += 256) {
        int c = lh[i];
        base[i] = c ? atomicAdd(&bincur[i], c) : 0;
        lh[i] = 0;
    }
    __syncthreads();
    for (int i = threadIdx.x; i < cnt; i += 256) {
        unsigned u = st[i];
        int b = (int)(u >> 23);
        int r = atomicAdd(&lh[b], 1);
        sorted[base[b] + r] = u;
    }
}

__global__ __launch_bounds__(256) void k_fine(
    const unsigned* __restrict__ sorted, const int* __restrict__ binstart,
    int* __restrict__ rowst, int* __restrict__ csrc, int n)
{
    int b = blockIdx.x;
    int s = binstart[b], t = binstart[b + 1];
    __shared__ int fh[128], fex[128], fcur[128];
    __shared__ int wtot;
    int tid = threadIdx.x;
    if (tid < 128) fh[tid] = 0;
    __syncthreads();
    for (int i = s + tid; i < t; i += 256)
        atomicAdd(&fh[(sorted[i] >> 16) & 127], 1);
    __syncthreads();
    if (tid < 128) {
        int lane = tid & 63;
        int x = fh[tid];
        int v = x;
#pragma unroll
        for (int off = 1; off < 64; off <<= 1) {
            int tv = __shfl_up(v, off, 64);
            if (lane >= off) v += tv;
        }
        fex[tid] = v - x;
        if (tid == 63) wtot = v;
    }
    __syncthreads();
    if (tid >= 64 && tid < 128) fex[tid] += wtot;
    __syncthreads();
    if (tid < 128) {
        int node = b * 128 + tid;
        if (node < n) rowst[node] = s + fex[tid];
        fcur[tid] = 0;
    }
    __syncthreads();
    for (int i = s + tid; i < t; i += 256) {
        unsigned u = sorted[i];
        int d = (u >> 16) & 127;
        int r = atomicAdd(&fcur[d], 1);
        csrc[s + fex[d] + r] = (int)(u & 0xFFFFu);
    }
}

// ---------------- W hi/lo bf16 split ----------------
__global__ void k_wsplit(const float* __restrict__ W, short* __restrict__ hi,
                         short* __restrict__ lo, int count) {
    int i = blockIdx.x * blockDim.x + threadIdx.x;
    if (i < count) {
        float v = W[i];
        unsigned short h = bf16_rne(v);
        float hf = __uint_as_float(((unsigned)h) << 16);
        unsigned short l = bf16_rne(v - hf);
        hi[i] = (short)h;
        lo[i] = (short)l;
    }
}

// ---------------- MFMA Linear, W staged in LDS ----------------
// R7: per-wave global W re-reads (200 MB L2, 16-line/inst) made this
// latency-bound at 42us, MfmaUtil 4%. Now: block stages Whi+Wlo into LDS
// once (coalesced), waves grid-stride over 16-row groups reading W frags
// via swizzled ds_read_b128 (quad q stored at q^(row&15): 2-way banks).
template <int DOUT, bool RELU>
__global__ __launch_bounds__(256) void k_linear_mfma(
    const float* __restrict__ X, const short* __restrict__ Whi, const short* __restrict__ Wlo,
    const float* __restrict__ B, _Float16* __restrict__ Hn,
    float* __restrict__ nrm, float* __restrict__ exself, int n)
{
    constexpr int NT = DOUT / 16;
    __shared__ __align__(16) short sWh[DOUT * 128];
    __shared__ __align__(16) short sWl[DOUT * 128];
    const int tid = threadIdx.x;

    // stage W (DOUT*16 quads of 16B), swizzled: quad q -> q ^ (row&15)
    for (int i = tid; i < DOUT * 16; i += 256) {
        int row = i >> 4, q = i & 15;
        bf16x8 vh = *reinterpret_cast<const bf16x8*>(Whi + row * 128 + q * 8);
        bf16x8 vl = *reinterpret_cast<const bf16x8*>(Wlo + row * 128 + q * 8);
        int qs = q ^ (row & 15);
        *reinterpret_cast<bf16x8*>(&sWh[row * 128 + qs * 8]) = vh;
        *reinterpret_cast<bf16x8*>(&sWl[row * 128 + qs * 8]) = vl;
    }
    __syncthreads();

    const int lane = tid & 63;
    const int r16 = lane & 15, kh = lane >> 4;
    const int nw = (n + 15) >> 4;

    for (int wt = blockIdx.x * 4 + (tid >> 6); wt < nw; wt += gridDim.x * 4) {
        const int rg = wt << 4;
        const int xrow = rg + r16;
        const bool rowok = xrow < n;
        const float* xp = X + (size_t)xrow * 128 + kh * 8;

        // preload + convert all 8 X slices (ks-major), full MLP
        bf16x8 ahi[4], alo[4];
#pragma unroll
        for (int ks = 0; ks < 4; ks++) {
            float4 xa = make_float4(0.f, 0.f, 0.f, 0.f);
            float4 xb = make_float4(0.f, 0.f, 0.f, 0.f);
            if (rowok) {
                xa = *reinterpret_cast<const float4*>(xp + ks * 32);
                xb = *reinterpret_cast<const float4*>(xp + ks * 32 + 4);
            }
            float xv[8] = {xa.x, xa.y, xa.z, xa.w, xb.x, xb.y, xb.z, xb.w};
#pragma unroll
            for (int j = 0; j < 8; j++) {
                float v = xv[j];
                if (RELU) v = fmaxf(v, 0.f);
                unsigned short h = bf16_rne(v);
                float hf = __uint_as_float(((unsigned)h) << 16);
                unsigned short l = bf16_rne(v - hf);
                ahi[ks][j] = (short)h;
                alo[ks][j] = (short)l;
            }
        }

        f32x4 acc[NT];
#pragma unroll
        for (int t = 0; t < NT; t++) acc[t] = (f32x4){0.f, 0.f, 0.f, 0.f};

#pragma unroll
        for (int ks = 0; ks < 4; ks++) {
            const int qs = (kh + ks * 4) ^ r16;
#pragma unroll
            for (int t = 0; t < NT; t++) {
                const int off = (t * 16 + r16) * 128 + qs * 8;
                bf16x8 bh = *reinterpret_cast<const bf16x8*>(&sWh[off]);
                bf16x8 bl = *reinterpret_cast<const bf16x8*>(&sWl[off]);
                acc[t] = __builtin_amdgcn_mfma_f32_16x16x32_bf16(ahi[ks], bh, acc[t], 0, 0, 0);
                acc[t] = __builtin_amdgcn_mfma_f32_16x16x32_bf16(alo[ks], bh, acc[t], 0, 0, 0);
                acc[t] = __builtin_amdgcn_mfma_f32_16x16x32_bf16(ahi[ks], bl, acc[t], 0, 0, 0);
            }
        }

        float ss[4] = {0.f, 0.f, 0.f, 0.f};
#pragma unroll
        for (int t = 0; t < NT; t++) {
            float bs = B[t * 16 + r16];
#pragma unroll
            for (int r = 0; r < 4; r++) {
                float v = acc[t][r] + bs;
                acc[t][r] = v;
                ss[r] += v * v;
            }
        }
#pragma unroll
        for (int m = 8; m > 0; m >>= 1) {
#pragma unroll
            for (int r = 0; r < 4; r++) ss[r] += __shfl_xor(ss[r], m, 64);
        }
        float nrmv[4], riv[4];
#pragma unroll
        for (int r = 0; r < 4; r++) {
            nrmv[r] = sqrtf(ss[r]);
            riv[r] = 1.0f / fmaxf(nrmv[r], 1e-12f);
        }
#pragma unroll
        for (int t = 0; t < NT; t++) {
#pragma unroll
            for (int r = 0; r < 4; r++) {
                int grow = rg + kh * 4 + r;
                if (grow < n)
                    Hn[(size_t)grow * DOUT + t * 16 + r16] = (_Float16)(acc[t][r] * riv[r]);
            }
        }
        if (r16 == 0) {
#pragma unroll
            for (int r = 0; r < 4; r++) {
                int grow = rg + kh * 4 + r;
                if (grow < n) {
                    float s = nrmv[r] * riv[r];
                    nrm[grow] = nrmv[r];
                    exself[grow] = __expf(s * s);
                }
            }
        }
    }
}

// ---------------- Fused attention aggregation (fp16 normalized rows) ----------------
__global__ __launch_bounds__(256) void k_agg128(
    const _Float16* __restrict__ Hn, const float* __restrict__ nrm, const float* __restrict__ exself,
    const int* __restrict__ rowst, const int* __restrict__ csrc,
    float* __restrict__ OUT, int n)
{
    const int wave = threadIdx.x >> 6, lane = threadIdx.x & 63;
    const int node = blockIdx.x * 4 + wave;
    if (node >= n) return;
    const int g = lane >> 4;
    const int t = lane & 15;

    half8_t hv = *reinterpret_cast<const half8_t*>(Hn + (size_t)node * 128 + t * 8);
    half2_t h2[4];
#pragma unroll
    for (int j = 0; j < 4; j++) h2[j] = (half2_t){hv[2 * j], hv[2 * j + 1]};
    float es = exself[node];
    float esn = es * nrm[node];
    float acc[8];
    float denom;
    if (g == 0) {
#pragma unroll
        for (int j = 0; j < 8; j++) acc[j] = esn * (float)hv[j];
        denom = es;
    } else {
#pragma unroll
        for (int j = 0; j < 8; j++) acc[j] = 0.f;
        denom = 0.f;
    }

    const int p0 = rowst[node], p1 = rowst[node + 1];
    const int iters = (p1 - p0 + 3) >> 2;
    int it = 0;
    for (; it + 2 <= iters; it += 2) {
        int pA = p0 + it * 4 + g, pB = pA + 4;
        bool vA = pA < p1, vB = pB < p1;
        int sA = vA ? csrc[pA] : node;
        int sB = vB ? csrc[pB] : node;
        half8_t av = *reinterpret_cast<const half8_t*>(Hn + (size_t)sA * 128 + t * 8);
        half8_t bv = *reinterpret_cast<const half8_t*>(Hn + (size_t)sB * 128 + t * 8);
        float nA = nrm[sA], nB = nrm[sB];
        half2_t da2 = (half2_t){hv[0], hv[1]} * (half2_t){av[0], av[1]};
        half2_t db2 = (half2_t){hv[0], hv[1]} * (half2_t){bv[0], bv[1]};
#pragma unroll
        for (int j = 1; j < 4; j++) {
            da2 += h2[j] * (half2_t){av[2 * j], av[2 * j + 1]};
            db2 += h2[j] * (half2_t){bv[2 * j], bv[2 * j + 1]};
        }
        float dA = (float)da2[0] + (float)da2[1];
        float dB = (float)db2[0] + (float)db2[1];
#pragma unroll
        for (int m = 8; m > 0; m >>= 1) {
            dA += __shfl_xor(dA, m, 64);
            dB += __shfl_xor(dB, m, 64);
        }
        float exA = vA ? __expf(dA) : 0.f;
        float exB = vB ? __expf(dB) : 0.f;
        denom += exA + exB;
        float wA = exA * nA, wB = exB * nB;
#pragma unroll
        for (int j = 0; j < 8; j++) acc[j] += wA * (float)av[j] + wB * (float)bv[j];
    }
    for (; it < iters; it++) {
        int pA = p0 + it * 4 + g;
        bool vA = pA < p1;
        int sA = vA ? csrc[pA] : node;
        half8_t av = *reinterpret_cast<const half8_t*>(Hn + (size_t)sA * 128 + t * 8);
        float nA = nrm[sA];
        half2_t da2 = (half2_t){hv[0], hv[1]} * (half2_t){av[0], av[1]};
#pragma unroll
        for (int j = 1; j < 4; j++) da2 += h2[j] * (half2_t){av[2 * j], av[2 * j + 1]};
        float dA = (float)da2[0] + (float)da2[1];
#pragma unroll
        for (int m = 8; m > 0; m >>= 1) dA += __shfl_xor(dA, m, 64);
        float exA = vA ? __expf(dA) : 0.f;
        denom += exA;
        float wA = exA * nA;
#pragma unroll
        for (int j = 0; j < 8; j++) acc[j] += wA * (float)av[j];
    }

#pragma unroll
    for (int j = 0; j < 8; j++) {
        acc[j] += __shfl_xor(acc[j], 16, 64);
        acc[j] += __shfl_xor(acc[j], 32, 64);
    }
    denom += __shfl_xor(denom, 16, 64);
    denom += __shfl_xor(denom, 32, 64);

    if (g == 0) {
        float inv = 1.0f / denom;
        float4 o0 = make_float4(acc[0] * inv, acc[1] * inv, acc[2] * inv, acc[3] * inv);
        float4 o1 = make_float4(acc[4] * inv, acc[5] * inv, acc[6] * inv, acc[7] * inv);
        float* op = OUT + (size_t)node * 128 + t * 8;
        *reinterpret_cast<float4*>(op) = o0;
        *reinterpret_cast<float4*>(op + 4) = o1;
    }
}

__global__ __launch_bounds__(256) void k_agg64_lsm(
    const _Float16* __restrict__ Hn, const float* __restrict__ nrm, const float* __restrict__ exself,
    const int* __restrict__ rowst, const int* __restrict__ csrc,
    float* __restrict__ OUT, int n)
{
    const int wave = threadIdx.x >> 6, lane = threadIdx.x & 63;
    const int node = blockIdx.x * 4 + wave;
    if (node >= n) return;
    const int g = lane >> 4;
    const int t = lane & 15;

    half4_t hv = *reinterpret_cast<const half4_t*>(Hn + (size_t)node * 64 + t * 4);
    half2_t h2[2] = {(half2_t){hv[0], hv[1]}, (half2_t){hv[2], hv[3]}};
    float es = exself[node];
    float esn = es * nrm[node];
    float acc[4];
    float denom;
    if (g == 0) {
#pragma unroll
        for (int j = 0; j < 4; j++) acc[j] = esn * (float)hv[j];
        denom = es;
    } else {
        acc[0] = acc[1] = acc[2] = acc[3] = 0.f;
        denom = 0.f;
    }

    const int p0 = rowst[node], p1 = rowst[node + 1];
    const int iters = (p1 - p0 + 3) >> 2;
    int it = 0;
    for (; it + 2 <= iters; it += 2) {
        int pA = p0 + it * 4 + g, pB = pA + 4;
        bool vA = pA < p1, vB = pB < p1;
        int sA = vA ? csrc[pA] : node;
        int sB = vB ? csrc[pB] : node;
        half4_t av = *reinterpret_cast<const half4_t*>(Hn + (size_t)sA * 64 + t * 4);
        half4_t bv = *reinterpret_cast<const half4_t*>(Hn + (size_t)sB * 64 + t * 4);
        float nA = nrm[sA], nB = nrm[sB];
        half2_t da2 = h2[0] * (half2_t){av[0], av[1]};
        half2_t db2 = h2[0] * (half2_t){bv[0], bv[1]};
        da2 += h2[1] * (half2_t){av[2], av[3]};
        db2 += h2[1] * (half2_t){bv[2], bv[3]};
        float dA = (float)da2[0] + (float)da2[1];
        float dB = (float)db2[0] + (float)db2[1];
#pragma unroll
        for (int m = 8; m > 0; m >>= 1) {
            dA += __shfl_xor(dA, m, 64);
            dB += __shfl_xor(dB, m, 64);
        }
        float exA = vA ? __expf(dA) : 0.f;
        float exB = vB ? __expf(dB) : 0.f;
        denom += exA + exB;
        float wA = exA * nA, wB = exB * nB;
#pragma unroll
        for (int j = 0; j < 4; j++) acc[j] += wA * (float)av[j] + wB * (float)bv[j];
    }
    for (; it < iters; it++) {
        int pA = p0 + it * 4 + g;
        bool vA = pA < p1;
        int sA = vA ? csrc[pA] : node;
        half4_t av = *reinterpret_cast<const half4_t*>(Hn + (size_t)sA * 64 + t * 4);
        float nA = nrm[sA];
        half2_t da2 = h2[0] * (half2_t){av[0], av[1]};
        da2 += h2[1] * (half2_t){av[2], av[3]};
        float dA = (float)da2[0] + (float)da2[1];
#pragma unroll
        for (int m = 8; m > 0; m >>= 1) dA += __shfl_xor(dA, m, 64);
        float exA = vA ? __expf(dA) : 0.f;
        denom += exA;
        float wA = exA * nA;
#pragma unroll
        for (int j = 0; j < 4; j++) acc[j] += wA * (float)av[j];
    }

#pragma unroll
    for (int j = 0; j < 4; j++) {
        acc[j] += __shfl_xor(acc[j], 16, 64);
        acc[j] += __shfl_xor(acc[j], 32, 64);
    }
    denom += __shfl_xor(denom, 16, 64);
    denom += __shfl_xor(denom, 32, 64);

    float inv = 1.0f / denom;
    float v0 = acc[0] * inv, v1 = acc[1] * inv, v2 = acc[2] * inv, v3 = acc[3] * inv;
    float mx = fmaxf(fmaxf(v0, v1), fmaxf(v2, v3));
#pragma unroll
    for (int m = 8; m > 0; m >>= 1) mx = fmaxf(mx, __shfl_xor(mx, m, 64));
    float se = __expf(v0 - mx) + __expf(v1 - mx) + __expf(v2 - mx) + __expf(v3 - mx);
#pragma unroll
    for (int m = 8; m > 0; m >>= 1) se += __shfl_xor(se, m, 64);
    float lse = mx + logf(se);
    if (g == 0) {
        float* op = OUT + (size_t)node * 64 + t * 4;
        *reinterpret_cast<float4*>(op) = make_float4(v0 - lse, v1 - lse, v2 - lse, v3 - lse);
    }
}

extern "C" void kernel_launch(void* const* d_in, const int* in_sizes, int n_in,
                              void* d_out, int out_size, void* d_ws, size_t ws_size,
                              hipStream_t stream)
{
    const float* x  = (const float*)d_in[0];
    const int*   ei = (const int*)d_in[1];
    const float* W1 = (const float*)d_in[2];
    const float* b1 = (const float*)d_in[3];
    const float* W2 = (const float*)d_in[4];
    const float* b2 = (const float*)d_in[5];
    const float* W3 = (const float*)d_in[6];
    const float* b3 = (const float*)d_in[7];
    float* out = (float*)d_out;

    const int n = in_sizes[0] / 128;
    const int e = in_sizes[1] / 2;
    const int* esrc = ei;
    const int* edst = ei + e;

    // 16B-aligned workspace carve
    uintptr_t wp = ((uintptr_t)d_ws + 15) & ~(uintptr_t)15;
#define CARVE(ty, name, count) ty* name = (ty*)wp; wp = (wp + (size_t)(count) * sizeof(ty) + 15) & ~(uintptr_t)15
    CARVE(float, conv, (size_t)n * 128);
    CARVE(_Float16, hn16, (size_t)n * 128);
    CARVE(float, nrm, n);
    CARVE(float, exs, n);
    CARVE(int, rowst, n + 1);
    CARVE(int, gh, 512);
    CARVE(int, binstart, 513);
    CARVE(int, bincur, 512);
    CARVE(unsigned, sorted, e);
    CARVE(int, csrc, e);
    CARVE(short, w1h, 128 * 128);
    CARVE(short, w1l, 128 * 128);
    CARVE(short, w2h, 128 * 128);
    CARVE(short, w2l, 128 * 128);
    CARVE(short, w3h, 64 * 128);
    CARVE(short, w3l, 64 * 128);
#undef CARVE

    const int nbin = (n + 127) >> 7;
    const int nchunk = (e + CSR_CHUNK - 1) / CSR_CHUNK;

    hipMemsetAsync(gh, 0, 512 * sizeof(int), stream);
    k_bh<<<nchunk, 256, 0, stream>>>(edst, gh, e, nbin);
    k_bscan<<<1, 512, 0, stream>>>(gh, binstart, bincur, rowst, e, nbin, n);
    k_scatter<<<nchunk, 256, 0, stream>>>(esrc, edst, bincur, sorted, e, nbin);
    k_fine<<<nbin, 256, 0, stream>>>(sorted, binstart, rowst, csrc, n);

    k_wsplit<<<64, 256, 0, stream>>>(W1, w1h, w1l, 128 * 128);
    k_wsplit<<<64, 256, 0, stream>>>(W2, w2h, w2l, 128 * 128);
    k_wsplit<<<32, 256, 0, stream>>>(W3, w3h, w3l, 64 * 128);

    const int lgrid = 512;             // 2 blocks/CU (64KB LDS each for DOUT=128)
    const int agrid = (n + 3) / 4;

    k_linear_mfma<128, false><<<lgrid, 256, 0, stream>>>(x, w1h, w1l, b1, hn16, nrm, exs, n);
    k_agg128<<<agrid, 256, 0, stream>>>(hn16, nrm, exs, rowst, csrc, conv, n);
    k_linear_mfma<128, true><<<lgrid, 256, 0, stream>>>(conv, w2h, w2l, b2, hn16, nrm, exs, n);
    k_agg128<<<agrid, 256, 0, stream>>>(hn16, nrm, exs, rowst, csrc, conv, n);
    k_linear_mfma<64, true><<<lgrid, 256, 0, stream>>>(conv, w3h, w3l, b3, hn16, nrm, exs, n);
    k_agg64_lsm<<<agrid, 256, 0, stream>>>(hn16, nrm, exs, rowst, csrc, out, n);
}

// Round 9
// 212.383 us; speedup vs baseline: 6.2438x; 1.0373x over previous
//
#include <hip/hip_runtime.h>

typedef float f32x4 __attribute__((ext_vector_type(4)));
typedef _Float16 half2_t __attribute__((ext_vector_type(2)));
typedef _Float16 half4_t __attribute__((ext_vector_type(4)));
typedef _Float16 half8_t __attribute__((ext_vector_type(8)));

// ================= CSR build via 2-level counting sort =================
// Edges packed as (dst<<16)|src (n <= 65536). Coarse bin = dst>>7.
#define CSR_CHUNK 4096

__global__ __launch_bounds__(256) void k_bh(const int* __restrict__ dst,
                                            int* __restrict__ gh, int e, int nbin) {
    __shared__ int lh[512];
    for (int i = threadIdx.x; i < nbin; i += 256) lh[i] = 0;
    __syncthreads();
    int lo = blockIdx.x * CSR_CHUNK;
    int hi = min(lo + CSR_CHUNK, e);
    for (int i = lo + threadIdx.x; i < hi; i += 256)
        atomicAdd(&lh[dst[i] >> 7], 1);
    __syncthreads();
    for (int i = threadIdx.x; i < nbin; i += 256)
        if (lh[i]) atomicAdd(&gh[i], lh[i]);
}

__global__ __launch_bounds__(512) void k_bscan(
    const int* __restrict__ gh, int* __restrict__ binstart, int* __restrict__ bincur,
    int* __restrict__ rowst, int e, int nbin, int n)
{
    int tid = threadIdx.x, lane = tid & 63, wv = tid >> 6;
    __shared__ int ws[8];
    int x = (tid < nbin) ? gh[tid] : 0;
    int v = x;
#pragma unroll
    for (int off = 1; off < 64; off <<= 1) {
        int t = __shfl_up(v, off, 64);
        if (lane >= off) v += t;
    }
    if (lane == 63) ws[wv] = v;
    __syncthreads();
    if (wv == 0) {
        int w = (lane < 8) ? ws[lane] : 0;
#pragma unroll
        for (int off = 1; off < 8; off <<= 1) {
            int t = __shfl_up(w, off, 64);
            if (lane >= off) w += t;
        }
        if (lane < 8) ws[lane] = w;
    }
    __syncthreads();
    if (wv > 0) v += ws[wv - 1];
    int excl = v - x;
    if (tid < nbin) { binstart[tid] = excl; bincur[tid] = excl; }
    if (tid == 0) { binstart[nbin] = e; rowst[n] = e; }
}

__global__ __launch_bounds__(256) void k_scatter(
    const int* __restrict__ src, const int* __restrict__ dst,
    int* __restrict__ bincur, unsigned* __restrict__ sorted, int e, int nbin)
{
    __shared__ unsigned st[CSR_CHUNK];
    __shared__ int lh[512];
    __shared__ int base[512];
    for (int i = threadIdx.x; i < nbin; i += 256) lh[i] = 0;
    __syncthreads();
    int lo = blockIdx.x * CSR_CHUNK;
    int cnt = min(lo + CSR_CHUNK, e) - lo;
    for (int i = threadIdx.x; i < cnt; i += 256) {
        int d = dst[lo + i], s = src[lo + i];
        st[i] = ((unsigned)d << 16) | (unsigned)s;
        atomicAdd(&lh[d >> 7], 1);
    }
    __syncthreads();
    for (int i = threadIdx.x; i < nbin; i += 256) {
        int c = lh[i];
        base[i] = c ? atomicAdd(&bincur[i], c) : 0;
        lh[i] = 0;
    }
    __syncthreads();
    for (int i = threadIdx.x; i < cnt; i += 256) {
        unsigned u = st[i];
        int b = (int)(u >> 23);
        int r = atomicAdd(&lh[b], 1);
        sorted[base[b] + r] = u;
    }
}

__global__ __launch_bounds__(256) void k_fine(
    const unsigned* __restrict__ sorted, const int* __restrict__ binstart,
    int* __restrict__ rowst, int* __restrict__ csrc, int n)
{
    int b = blockIdx.x;
    int s = binstart[b], t = binstart[b + 1];
    __shared__ int fh[128], fex[128], fcur[128];
    __shared__ int wtot;
    int tid = threadIdx.x;
    if (tid < 128) fh[tid] = 0;
    __syncthreads();
    for (int i = s + tid; i < t; i += 256)
        atomicAdd(&fh[(sorted[i] >> 16) & 127], 1);
    __syncthreads();
    if (tid < 128) {
        int lane = tid & 63;
        int x = fh[tid];
        int v = x;
#pragma unroll
        for (int off = 1; off < 64; off <<= 1) {
            int tv = __shfl_up(v, off, 64);
            if (lane >= off) v += tv;
        }
        fex[tid] = v - x;
        if (tid == 63) wtot = v;
    }
    __syncthreads();
    if (tid >= 64 && tid < 128) fex[tid] += wtot;
    __syncthreads();
    if (tid < 128) {
        int node = b * 128 + tid;
        if (node < n) rowst[node] = s + fex[tid];
        fcur[tid] = 0;
    }
    __syncthreads();
    for (int i = s + tid; i < t; i += 256) {
        unsigned u = sorted[i];
        int d = (u >> 16) & 127;
        int r = atomicAdd(&fcur[d], 1);
        csrc[s + fex[d] + r] = (int)(u & 0xFFFFu);
    }
}

// ---------------- fp32 -> fp16 plane (layer-1 X) ----------------
__global__ void k_half(const float* __restrict__ X, _Float16* __restrict__ O, int count4) {
    for (int i = blockIdx.x * blockDim.x + threadIdx.x; i < count4; i += gridDim.x * blockDim.x) {
        float4 v = reinterpret_cast<const float4*>(X)[i];
        half4_t o = {(_Float16)v.x, (_Float16)v.y, (_Float16)v.z, (_Float16)v.w};
        *reinterpret_cast<half4_t*>(O + (size_t)i * 4) = o;
    }
}

// ---------------- W fp16 hi/lo split ----------------
__global__ void k_wsplit16(const float* __restrict__ W, _Float16* __restrict__ hi,
                           _Float16* __restrict__ lo, int count) {
    for (int i = blockIdx.x * blockDim.x + threadIdx.x; i < count; i += gridDim.x * blockDim.x) {
        float v = W[i];
        _Float16 h = (_Float16)v;
        hi[i] = h;
        lo[i] = (_Float16)(v - (float)h);
    }
}

// ---------------- MFMA Linear (fp16 X, fp16 hi/lo W) + L2-norm prep ----------------
// R8 lesson: LDS-W vs L2-W both 41us, MfmaUtil 4% -> invariant cost was the
// fp32 X loads + in-reg bf16 hi/lo conversion + 96 MFMA/64 ds per group.
// Now: X is fp16 (half the bytes, zero conversion), W fp16 hi+lo (2 MFMA/tile),
// explicit X double-buffer prefetch across the grid-stride loop.
template <int DOUT>
__global__ __launch_bounds__(256) void k_linear_mfma(
    const _Float16* __restrict__ Xf, const _Float16* __restrict__ Whf,
    const _Float16* __restrict__ Wlf, const float* __restrict__ B,
    _Float16* __restrict__ Hn, float* __restrict__ nrm, float* __restrict__ exself, int n)
{
    constexpr int NT = DOUT / 16;
    __shared__ __align__(16) _Float16 sWh[DOUT * 128];
    __shared__ __align__(16) _Float16 sWl[DOUT * 128];
    const int tid = threadIdx.x;

    // stage W, quad q -> q ^ (row&15)
    for (int i = tid; i < DOUT * 16; i += 256) {
        int row = i >> 4, q = i & 15;
        half8_t vh = *reinterpret_cast<const half8_t*>(Whf + row * 128 + q * 8);
        half8_t vl = *reinterpret_cast<const half8_t*>(Wlf + row * 128 + q * 8);
        int qs = q ^ (row & 15);
        *reinterpret_cast<half8_t*>(&sWh[row * 128 + qs * 8]) = vh;
        *reinterpret_cast<half8_t*>(&sWl[row * 128 + qs * 8]) = vl;
    }
    __syncthreads();

    const int lane = tid & 63;
    const int r16 = lane & 15, kh = lane >> 4;
    const int nw = (n + 15) >> 4;
    const int stride = gridDim.x * 4;
    int wt = blockIdx.x * 4 + (tid >> 6);

    half8_t a[4];
    if (wt < nw) {
        const _Float16* px = Xf + (size_t)((wt << 4) + r16) * 128 + kh * 8;
#pragma unroll
        for (int ks = 0; ks < 4; ks++) a[ks] = *reinterpret_cast<const half8_t*>(px + ks * 32);
    }

    for (; wt < nw; wt += stride) {
        const int rg = wt << 4;
        // prefetch next row-group's X
        half8_t nx[4];
        const int wt2 = wt + stride;
        if (wt2 < nw) {
            const _Float16* px = Xf + (size_t)((wt2 << 4) + r16) * 128 + kh * 8;
#pragma unroll
            for (int ks = 0; ks < 4; ks++) nx[ks] = *reinterpret_cast<const half8_t*>(px + ks * 32);
        }

        f32x4 acc[NT];
#pragma unroll
        for (int t = 0; t < NT; t++) acc[t] = (f32x4){0.f, 0.f, 0.f, 0.f};

#pragma unroll
        for (int ks = 0; ks < 4; ks++) {
            const int qs = (kh + ks * 4) ^ r16;
#pragma unroll
            for (int t = 0; t < NT; t++) {
                const int off = (t * 16 + r16) * 128 + qs * 8;
                half8_t bh = *reinterpret_cast<const half8_t*>(&sWh[off]);
                half8_t bl = *reinterpret_cast<const half8_t*>(&sWl[off]);
                acc[t] = __builtin_amdgcn_mfma_f32_16x16x32_f16(a[ks], bh, acc[t], 0, 0, 0);
                acc[t] = __builtin_amdgcn_mfma_f32_16x16x32_f16(a[ks], bl, acc[t], 0, 0, 0);
            }
        }

        float ss[4] = {0.f, 0.f, 0.f, 0.f};
#pragma unroll
        for (int t = 0; t < NT; t++) {
            float bs = B[t * 16 + r16];
#pragma unroll
            for (int r = 0; r < 4; r++) {
                float v = acc[t][r] + bs;
                acc[t][r] = v;
                ss[r] += v * v;
            }
        }
#pragma unroll
        for (int m = 8; m > 0; m >>= 1) {
#pragma unroll
            for (int r = 0; r < 4; r++) ss[r] += __shfl_xor(ss[r], m, 64);
        }
        float nrmv[4], riv[4];
#pragma unroll
        for (int r = 0; r < 4; r++) {
            nrmv[r] = sqrtf(ss[r]);
            riv[r] = 1.0f / fmaxf(nrmv[r], 1e-12f);
        }
#pragma unroll
        for (int t = 0; t < NT; t++) {
#pragma unroll
            for (int r = 0; r < 4; r++) {
                int grow = rg + kh * 4 + r;
                if (grow < n)
                    Hn[(size_t)grow * DOUT + t * 16 + r16] = (_Float16)(acc[t][r] * riv[r]);
            }
        }
        if (r16 == 0) {
#pragma unroll
            for (int r = 0; r < 4; r++) {
                int grow = rg + kh * 4 + r;
                if (grow < n) {
                    float s = nrmv[r] * riv[r];
                    nrm[grow] = nrmv[r];
                    exself[grow] = __expf(s * s);
                }
            }
        }
#pragma unroll
        for (int ks = 0; ks < 4; ks++) a[ks] = nx[ks];
    }
}

// ---------------- Fused attention aggregation (fp16 normalized rows) ----------------
// Epilogue fuses ReLU + fp16 convert, writing the next layer's X plane.
__global__ __launch_bounds__(256) void k_agg128(
    const _Float16* __restrict__ Hn, const float* __restrict__ nrm, const float* __restrict__ exself,
    const int* __restrict__ rowst, const int* __restrict__ csrc,
    _Float16* __restrict__ Oxf, int n)
{
    const int wave = threadIdx.x >> 6, lane = threadIdx.x & 63;
    const int node = blockIdx.x * 4 + wave;
    if (node >= n) return;
    const int g = lane >> 4;
    const int t = lane & 15;

    half8_t hv = *reinterpret_cast<const half8_t*>(Hn + (size_t)node * 128 + t * 8);
    half2_t h2[4];
#pragma unroll
    for (int j = 0; j < 4; j++) h2[j] = (half2_t){hv[2 * j], hv[2 * j + 1]};
    float es = exself[node];
    float esn = es * nrm[node];
    float acc[8];
    float denom;
    if (g == 0) {
#pragma unroll
        for (int j = 0; j < 8; j++) acc[j] = esn * (float)hv[j];
        denom = es;
    } else {
#pragma unroll
        for (int j = 0; j < 8; j++) acc[j] = 0.f;
        denom = 0.f;
    }

    const int p0 = rowst[node], p1 = rowst[node + 1];
    const int iters = (p1 - p0 + 3) >> 2;
    int it = 0;
    for (; it + 2 <= iters; it += 2) {
        int pA = p0 + it * 4 + g, pB = pA + 4;
        bool vA = pA < p1, vB = pB < p1;
        int sA = vA ? csrc[pA] : node;
        int sB = vB ? csrc[pB] : node;
        half8_t av = *reinterpret_cast<const half8_t*>(Hn + (size_t)sA * 128 + t * 8);
        half8_t bv = *reinterpret_cast<const half8_t*>(Hn + (size_t)sB * 128 + t * 8);
        float nA = nrm[sA], nB = nrm[sB];
        half2_t da2 = (half2_t){hv[0], hv[1]} * (half2_t){av[0], av[1]};
        half2_t db2 = (half2_t){hv[0], hv[1]} * (half2_t){bv[0], bv[1]};
#pragma unroll
        for (int j = 1; j < 4; j++) {
            da2 += h2[j] * (half2_t){av[2 * j], av[2 * j + 1]};
            db2 += h2[j] * (half2_t){bv[2 * j], bv[2 * j + 1]};
        }
        float dA = (float)da2[0] + (float)da2[1];
        float dB = (float)db2[0] + (float)db2[1];
#pragma unroll
        for (int m = 8; m > 0; m >>= 1) {
            dA += __shfl_xor(dA, m, 64);
            dB += __shfl_xor(dB, m, 64);
        }
        float exA = vA ? __expf(dA) : 0.f;
        float exB = vB ? __expf(dB) : 0.f;
        denom += exA + exB;
        float wA = exA * nA, wB = exB * nB;
#pragma unroll
        for (int j = 0; j < 8; j++) acc[j] += wA * (float)av[j] + wB * (float)bv[j];
    }
    for (; it < iters; it++) {
        int pA = p0 + it * 4 + g;
        bool vA = pA < p1;
        int sA = vA ? csrc[pA] : node;
        half8_t av = *reinterpret_cast<const half8_t*>(Hn + (size_t)sA * 128 + t * 8);
        float nA = nrm[sA];
        half2_t da2 = (half2_t){hv[0], hv[1]} * (half2_t){av[0], av[1]};
#pragma unroll
        for (int j = 1; j < 4; j++) da2 += h2[j] * (half2_t){av[2 * j], av[2 * j + 1]};
        float dA = (float)da2[0] + (float)da2[1];
#pragma unroll
        for (int m = 8; m > 0; m >>= 1) dA += __shfl_xor(dA, m, 64);
        float exA = vA ? __expf(dA) : 0.f;
        denom += exA;
        float wA = exA * nA;
#pragma unroll
        for (int j = 0; j < 8; j++) acc[j] += wA * (float)av[j];
    }

#pragma unroll
    for (int j = 0; j < 8; j++) {
        acc[j] += __shfl_xor(acc[j], 16, 64);
        acc[j] += __shfl_xor(acc[j], 32, 64);
    }
    denom += __shfl_xor(denom, 16, 64);
    denom += __shfl_xor(denom, 32, 64);

    if (g == 0) {
        float inv = 1.0f / denom;
        half8_t o;
#pragma unroll
        for (int j = 0; j < 8; j++)
            o[j] = (_Float16)fmaxf(acc[j] * inv, 0.f);   // fused ReLU + fp16
        *reinterpret_cast<half8_t*>(Oxf + (size_t)node * 128 + t * 8) = o;
    }
}

__global__ __launch_bounds__(256) void k_agg64_lsm(
    const _Float16* __restrict__ Hn, const float* __restrict__ nrm, const float* __restrict__ exself,
    const int* __restrict__ rowst, const int* __restrict__ csrc,
    float* __restrict__ OUT, int n)
{
    const int wave = threadIdx.x >> 6, lane = threadIdx.x & 63;
    const int node = blockIdx.x * 4 + wave;
    if (node >= n) return;
    const int g = lane >> 4;
    const int t = lane & 15;

    half4_t hv = *reinterpret_cast<const half4_t*>(Hn + (size_t)node * 64 + t * 4);
    half2_t h2[2] = {(half2_t){hv[0], hv[1]}, (half2_t){hv[2], hv[3]}};
    float es = exself[node];
    float esn = es * nrm[node];
    float acc[4];
    float denom;
    if (g == 0) {
#pragma unroll
        for (int j = 0; j < 4; j++) acc[j] = esn * (float)hv[j];
        denom = es;
    } else {
        acc[0] = acc[1] = acc[2] = acc[3] = 0.f;
        denom = 0.f;
    }

    const int p0 = rowst[node], p1 = rowst[node + 1];
    const int iters = (p1 - p0 + 3) >> 2;
    int it = 0;
    for (; it + 2 <= iters; it += 2) {
        int pA = p0 + it * 4 + g, pB = pA + 4;
        bool vA = pA < p1, vB = pB < p1;
        int sA = vA ? csrc[pA] : node;
        int sB = vB ? csrc[pB] : node;
        half4_t av = *reinterpret_cast<const half4_t*>(Hn + (size_t)sA * 64 + t * 4);
        half4_t bv = *reinterpret_cast<const half4_t*>(Hn + (size_t)sB * 64 + t * 4);
        float nA = nrm[sA], nB = nrm[sB];
        half2_t da2 = h2[0] * (half2_t){av[0], av[1]};
        half2_t db2 = h2[0] * (half2_t){bv[0], bv[1]};
        da2 += h2[1] * (half2_t){av[2], av[3]};
        db2 += h2[1] * (half2_t){bv[2], bv[3]};
        float dA = (float)da2[0] + (float)da2[1];
        float dB = (float)db2[0] + (float)db2[1];
#pragma unroll
        for (int m = 8; m > 0; m >>= 1) {
            dA += __shfl_xor(dA, m, 64);
            dB += __shfl_xor(dB, m, 64);
        }
        float exA = vA ? __expf(dA) : 0.f;
        float exB = vB ? __expf(dB) : 0.f;
        denom += exA + exB;
        float wA = exA * nA, wB = exB * nB;
#pragma unroll
        for (int j = 0; j < 4; j++) acc[j] += wA * (float)av[j] + wB * (float)bv[j];
    }
    for (; it < iters; it++) {
        int pA = p0 + it * 4 + g;
        bool vA = pA < p1;
        int sA = vA ? csrc[pA] : node;
        half4_t av = *reinterpret_cast<const half4_t*>(Hn + (size_t)sA * 64 + t * 4);
        float nA = nrm[sA];
        half2_t da2 = h2[0] * (half2_t){av[0], av[1]};
        da2 += h2[1] * (half2_t){av[2], av[3]};
        float dA = (float)da2[0] + (float)da2[1];
#pragma unroll
        for (int m = 8; m > 0; m >>= 1) dA += __shfl_xor(dA, m, 64);
        float exA = vA ? __expf(dA) : 0.f;
        denom += exA;
        float wA = exA * nA;
#pragma unroll
        for (int j = 0; j < 4; j++) acc[j] += wA * (float)av[j];
    }

#pragma unroll
    for (int j = 0; j < 4; j++) {
        acc[j] += __shfl_xor(acc[j], 16, 64);
        acc[j] += __shfl_xor(acc[j], 32, 64);
    }
    denom += __shfl_xor(denom, 16, 64);
    denom += __shfl_xor(denom, 32, 64);

    float inv = 1.0f / denom;
    float v0 = acc[0] * inv, v1 = acc[1] * inv, v2 = acc[2] * inv, v3 = acc[3] * inv;
    float mx = fmaxf(fmaxf(v0, v1), fmaxf(v2, v3));
#pragma unroll
    for (int m = 8; m > 0; m >>= 1) mx = fmaxf(mx, __shfl_xor(mx, m, 64));
    float se = __expf(v0 - mx) + __expf(v1 - mx) + __expf(v2 - mx) + __expf(v3 - mx);
#pragma unroll
    for (int m = 8; m > 0; m >>= 1) se += __shfl_xor(se, m, 64);
    float lse = mx + logf(se);
    if (g == 0) {
        float* op = OUT + (size_t)node * 64 + t * 4;
        *reinterpret_cast<float4*>(op) = make_float4(v0 - lse, v1 - lse, v2 - lse, v3 - lse);
    }
}

extern "C" void kernel_launch(void* const* d_in, const int* in_sizes, int n_in,
                              void* d_out, int out_size, void* d_ws, size_t ws_size,
                              hipStream_t stream)
{
    const float* x  = (const float*)d_in[0];
    const int*   ei = (const int*)d_in[1];
    const float* W1 = (const float*)d_in[2];
    const float* b1 = (const float*)d_in[3];
    const float* W2 = (const float*)d_in[4];
    const float* b2 = (const float*)d_in[5];
    const float* W3 = (const float*)d_in[6];
    const float* b3 = (const float*)d_in[7];
    float* out = (float*)d_out;

    const int n = in_sizes[0] / 128;
    const int e = in_sizes[1] / 2;
    const int* esrc = ei;
    const int* edst = ei + e;
    const int npad = (n + 15) & ~15;   // padded rows for 16-row MFMA groups

    uintptr_t wp = ((uintptr_t)d_ws + 15) & ~(uintptr_t)15;
#define CARVE(ty, name, count) ty* name = (ty*)wp; wp = (wp + (size_t)(count) * sizeof(ty) + 15) & ~(uintptr_t)15
    CARVE(_Float16, xf, (size_t)npad * 128);    // current layer input (fp16)
    CARVE(_Float16, hn16, (size_t)npad * 128);  // normalized features (fp16)
    CARVE(float, nrm, n);
    CARVE(float, exs, n);
    CARVE(int, rowst, n + 1);
    CARVE(int, gh, 512);
    CARVE(int, binstart, 513);
    CARVE(int, bincur, 512);
    CARVE(unsigned, sorted, e);
    CARVE(int, csrc, e);
    CARVE(_Float16, w1h, 128 * 128);
    CARVE(_Float16, w1l, 128 * 128);
    CARVE(_Float16, w2h, 128 * 128);
    CARVE(_Float16, w2l, 128 * 128);
    CARVE(_Float16, w3h, 64 * 128);
    CARVE(_Float16, w3l, 64 * 128);
#undef CARVE

    const int nbin = (n + 127) >> 7;
    const int nchunk = (e + CSR_CHUNK - 1) / CSR_CHUNK;

    hipMemsetAsync(gh, 0, 512 * sizeof(int), stream);
    k_bh<<<nchunk, 256, 0, stream>>>(edst, gh, e, nbin);
    k_bscan<<<1, 512, 0, stream>>>(gh, binstart, bincur, rowst, e, nbin, n);
    k_scatter<<<nchunk, 256, 0, stream>>>(esrc, edst, bincur, sorted, e, nbin);
    k_fine<<<nbin, 256, 0, stream>>>(sorted, binstart, rowst, csrc, n);

    k_half<<<1024, 256, 0, stream>>>(x, xf, n * 32);
    k_wsplit16<<<64, 256, 0, stream>>>(W1, w1h, w1l, 128 * 128);
    k_wsplit16<<<64, 256, 0, stream>>>(W2, w2h, w2l, 128 * 128);
    k_wsplit16<<<32, 256, 0, stream>>>(W3, w3h, w3l, 64 * 128);

    const int lgrid = 512;
    const int agrid = (n + 3) / 4;

    k_linear_mfma<128><<<lgrid, 256, 0, stream>>>(xf, w1h, w1l, b1, hn16, nrm, exs, n);
    k_agg128<<<agrid, 256, 0, stream>>>(hn16, nrm, exs, rowst, csrc, xf, n);
    k_linear_mfma<128><<<lgrid, 256, 0, stream>>>(xf, w2h, w2l, b2, hn16, nrm, exs, n);
    k_agg128<<<agrid, 256, 0, stream>>>(hn16, nrm, exs, rowst, csrc, xf, n);
    k_linear_mfma<64><<<lgrid, 256, 0, stream>>>(xf, w3h, w3l, b3, hn16, nrm, exs, n);
    k_agg64_lsm<<<agrid, 256, 0, stream>>>(hn16, nrm, exs, rowst, csrc, out, n);
}

// Round 10
// 211.716 us; speedup vs baseline: 6.2635x; 1.0032x over previous
//
#include <hip/hip_runtime.h>

typedef float f32x4 __attribute__((ext_vector_type(4)));
typedef _Float16 half2_t __attribute__((ext_vector_type(2)));
typedef _Float16 half4_t __attribute__((ext_vector_type(4)));
typedef _Float16 half8_t __attribute__((ext_vector_type(8)));

// ================= CSR build via 2-level counting sort =================
// Edges packed as (dst<<16)|src (n <= 65536). Coarse bin = dst>>7.
#define CSR_CHUNK 4096

__global__ __launch_bounds__(256) void k_bh(const int* __restrict__ dst,
                                            int* __restrict__ gh, int e, int nbin) {
    __shared__ int lh[512];
    for (int i = threadIdx.x; i < nbin; i += 256) lh[i] = 0;
    __syncthreads();
    int lo = blockIdx.x * CSR_CHUNK;
    int hi = min(lo + CSR_CHUNK, e);
    for (int i = lo + threadIdx.x; i < hi; i += 256)
        atomicAdd(&lh[dst[i] >> 7], 1);
    __syncthreads();
    for (int i = threadIdx.x; i < nbin; i += 256)
        if (lh[i]) atomicAdd(&gh[i], lh[i]);
}

__global__ __launch_bounds__(512) void k_bscan(
    const int* __restrict__ gh, int* __restrict__ binstart, int* __restrict__ bincur,
    int* __restrict__ rowst, int e, int nbin, int n)
{
    int tid = threadIdx.x, lane = tid & 63, wv = tid >> 6;
    __shared__ int ws[8];
    int x = (tid < nbin) ? gh[tid] : 0;
    int v = x;
#pragma unroll
    for (int off = 1; off < 64; off <<= 1) {
        int t = __shfl_up(v, off, 64);
        if (lane >= off) v += t;
    }
    if (lane == 63) ws[wv] = v;
    __syncthreads();
    if (wv == 0) {
        int w = (lane < 8) ? ws[lane] : 0;
#pragma unroll
        for (int off = 1; off < 8; off <<= 1) {
            int t = __shfl_up(w, off, 64);
            if (lane >= off) w += t;
        }
        if (lane < 8) ws[lane] = w;
    }
    __syncthreads();
    if (wv > 0) v += ws[wv - 1];
    int excl = v - x;
    if (tid < nbin) { binstart[tid] = excl; bincur[tid] = excl; }
    if (tid == 0) { binstart[nbin] = e; rowst[n] = e; }
}

__global__ __launch_bounds__(256) void k_scatter(
    const int* __restrict__ src, const int* __restrict__ dst,
    int* __restrict__ bincur, unsigned* __restrict__ sorted, int e, int nbin)
{
    __shared__ unsigned st[CSR_CHUNK];
    __shared__ int lh[512];
    __shared__ int base[512];
    for (int i = threadIdx.x; i < nbin; i += 256) lh[i] = 0;
    __syncthreads();
    int lo = blockIdx.x * CSR_CHUNK;
    int cnt = min(lo + CSR_CHUNK, e) - lo;
    for (int i = threadIdx.x; i < cnt; i += 256) {
        int d = dst[lo + i], s = src[lo + i];
        st[i] = ((unsigned)d << 16) | (unsigned)s;
        atomicAdd(&lh[d >> 7], 1);
    }
    __syncthreads();
    for (int i = threadIdx.x; i < nbin; i += 256) {
        int c = lh[i];
        base[i] = c ? atomicAdd(&bincur[i], c) : 0;
        lh[i] = 0;
    }
    __syncthreads();
    for (int i = threadIdx.x; i < cnt; i += 256) {
        unsigned u = st[i];
        int b = (int)(u >> 23);
        int r = atomicAdd(&lh[b], 1);
        sorted[base[b] + r] = u;
    }
}

__global__ __launch_bounds__(256) void k_fine(
    const unsigned* __restrict__ sorted, const int* __restrict__ binstart,
    int* __restrict__ rowst, int* __restrict__ csrc, int n)
{
    int b = blockIdx.x;
    int s = binstart[b], t = binstart[b + 1];
    __shared__ int fh[128], fex[128], fcur[128];
    __shared__ int wtot;
    int tid = threadIdx.x;
    if (tid < 128) fh[tid] = 0;
    __syncthreads();
    for (int i = s + tid; i < t; i += 256)
        atomicAdd(&fh[(sorted[i] >> 16) & 127], 1);
    __syncthreads();
    if (tid < 128) {
        int lane = tid & 63;
        int x = fh[tid];
        int v = x;
#pragma unroll
        for (int off = 1; off < 64; off <<= 1) {
            int tv = __shfl_up(v, off, 64);
            if (lane >= off) v += tv;
        }
        fex[tid] = v - x;
        if (tid == 63) wtot = v;
    }
    __syncthreads();
    if (tid >= 64 && tid < 128) fex[tid] += wtot;
    __syncthreads();
    if (tid < 128) {
        int node = b * 128 + tid;
        if (node < n) rowst[node] = s + fex[tid];
        fcur[tid] = 0;
    }
    __syncthreads();
    for (int i = s + tid; i < t; i += 256) {
        unsigned u = sorted[i];
        int d = (u >> 16) & 127;
        int r = atomicAdd(&fcur[d], 1);
        csrc[s + fex[d] + r] = (int)(u & 0xFFFFu);
    }
}

// ---------------- All three W fp16 hi/lo splits in one launch ----------------
__global__ void k_wsplit_all(const float* __restrict__ W1, const float* __restrict__ W2,
                             const float* __restrict__ W3,
                             _Float16* __restrict__ w1h, _Float16* __restrict__ w1l,
                             _Float16* __restrict__ w2h, _Float16* __restrict__ w2l,
                             _Float16* __restrict__ w3h, _Float16* __restrict__ w3l) {
    const int N1 = 128 * 128, N2 = 128 * 128, N3 = 64 * 128;
    for (int i = blockIdx.x * blockDim.x + threadIdx.x; i < N1 + N2 + N3;
         i += gridDim.x * blockDim.x) {
        const float* W; _Float16 *ph, *pl; int j;
        if (i < N1)            { W = W1; ph = w1h; pl = w1l; j = i; }
        else if (i < N1 + N2)  { W = W2; ph = w2h; pl = w2l; j = i - N1; }
        else                   { W = W3; ph = w3h; pl = w3l; j = i - N1 - N2; }
        float v = W[j];
        _Float16 h = (_Float16)v;
        ph[j] = h;
        pl[j] = (_Float16)(v - (float)h);
    }
}

// ---------------- MFMA Linear (fp16 hi/lo W in LDS) + L2-norm prep ----------------
// F32IN=true: reads fp32 X and converts in-register (layer 1; kills k_half).
template <int DOUT, bool F32IN>
__global__ __launch_bounds__(256) void k_linear_mfma(
    const void* __restrict__ Xv, const _Float16* __restrict__ Whf,
    const _Float16* __restrict__ Wlf, const float* __restrict__ B,
    _Float16* __restrict__ Hn, float* __restrict__ nrm, float* __restrict__ exself, int n)
{
    constexpr int NT = DOUT / 16;
    __shared__ __align__(16) _Float16 sWh[DOUT * 128];
    __shared__ __align__(16) _Float16 sWl[DOUT * 128];
    const int tid = threadIdx.x;

    for (int i = tid; i < DOUT * 16; i += 256) {
        int row = i >> 4, q = i & 15;
        half8_t vh = *reinterpret_cast<const half8_t*>(Whf + row * 128 + q * 8);
        half8_t vl = *reinterpret_cast<const half8_t*>(Wlf + row * 128 + q * 8);
        int qs = q ^ (row & 15);
        *reinterpret_cast<half8_t*>(&sWh[row * 128 + qs * 8]) = vh;
        *reinterpret_cast<half8_t*>(&sWl[row * 128 + qs * 8]) = vl;
    }
    __syncthreads();

    const int lane = tid & 63;
    const int r16 = lane & 15, kh = lane >> 4;
    const int nw = (n + 15) >> 4;
    const int stride = gridDim.x * 4;
    int wt = blockIdx.x * 4 + (tid >> 6);

    const float* Xf32 = (const float*)Xv;
    const _Float16* Xf16 = (const _Float16*)Xv;

    auto loadX = [&](int group, half8_t a[4]) {
        if (F32IN) {
            const float* px = Xf32 + (size_t)((group << 4) + r16) * 128 + kh * 8;
#pragma unroll
            for (int ks = 0; ks < 4; ks++) {
                float4 xa = *reinterpret_cast<const float4*>(px + ks * 32);
                float4 xb = *reinterpret_cast<const float4*>(px + ks * 32 + 4);
                a[ks] = (half8_t){(_Float16)xa.x, (_Float16)xa.y, (_Float16)xa.z, (_Float16)xa.w,
                                  (_Float16)xb.x, (_Float16)xb.y, (_Float16)xb.z, (_Float16)xb.w};
            }
        } else {
            const _Float16* px = Xf16 + (size_t)((group << 4) + r16) * 128 + kh * 8;
#pragma unroll
            for (int ks = 0; ks < 4; ks++)
                a[ks] = *reinterpret_cast<const half8_t*>(px + ks * 32);
        }
    };

    half8_t a[4];
    if (wt < nw) loadX(wt, a);

    for (; wt < nw; wt += stride) {
        const int rg = wt << 4;
        half8_t nx[4];
        const int wt2 = wt + stride;
        if (wt2 < nw) loadX(wt2, nx);

        f32x4 acc[NT];
#pragma unroll
        for (int t = 0; t < NT; t++) acc[t] = (f32x4){0.f, 0.f, 0.f, 0.f};

#pragma unroll
        for (int ks = 0; ks < 4; ks++) {
            const int qs = (kh + ks * 4) ^ r16;
#pragma unroll
            for (int t = 0; t < NT; t++) {
                const int off = (t * 16 + r16) * 128 + qs * 8;
                half8_t bh = *reinterpret_cast<const half8_t*>(&sWh[off]);
                half8_t bl = *reinterpret_cast<const half8_t*>(&sWl[off]);
                acc[t] = __builtin_amdgcn_mfma_f32_16x16x32_f16(a[ks], bh, acc[t], 0, 0, 0);
                acc[t] = __builtin_amdgcn_mfma_f32_16x16x32_f16(a[ks], bl, acc[t], 0, 0, 0);
            }
        }

        float ss[4] = {0.f, 0.f, 0.f, 0.f};
#pragma unroll
        for (int t = 0; t < NT; t++) {
            float bs = B[t * 16 + r16];
#pragma unroll
            for (int r = 0; r < 4; r++) {
                float v = acc[t][r] + bs;
                acc[t][r] = v;
                ss[r] += v * v;
            }
        }
#pragma unroll
        for (int m = 8; m > 0; m >>= 1) {
#pragma unroll
            for (int r = 0; r < 4; r++) ss[r] += __shfl_xor(ss[r], m, 64);
        }
        float nrmv[4], riv[4];
#pragma unroll
        for (int r = 0; r < 4; r++) {
            nrmv[r] = sqrtf(ss[r]);
            riv[r] = 1.0f / fmaxf(nrmv[r], 1e-12f);
        }
#pragma unroll
        for (int t = 0; t < NT; t++) {
#pragma unroll
            for (int r = 0; r < 4; r++) {
                int grow = rg + kh * 4 + r;
                if (grow < n)
                    Hn[(size_t)grow * DOUT + t * 16 + r16] = (_Float16)(acc[t][r] * riv[r]);
            }
        }
        if (r16 == 0) {
#pragma unroll
            for (int r = 0; r < 4; r++) {
                int grow = rg + kh * 4 + r;
                if (grow < n) {
                    float s = nrmv[r] * riv[r];
                    nrm[grow] = nrmv[r];
                    exself[grow] = __expf(s * s);
                }
            }
        }
#pragma unroll
        for (int ks = 0; ks < 4; ks++) a[ks] = nx[ks];
    }
}

// ---------------- Fused attention aggregation (fp16 rows, SW-pipelined) ----------------
// R9: edge loop issued gathers then consumed them -> ~200cy L2 latency exposed
// per iter. Now: iteration k's body first issues ALL of iteration k+1's loads
// (csrc idx, row gathers, nrm), then computes k from registers.
__global__ __launch_bounds__(256) void k_agg128(
    const _Float16* __restrict__ Hn, const float* __restrict__ nrm, const float* __restrict__ exself,
    const int* __restrict__ rowst, const int* __restrict__ csrc,
    _Float16* __restrict__ Oxf, int n)
{
    const int wave = threadIdx.x >> 6, lane = threadIdx.x & 63;
    const int node = blockIdx.x * 4 + wave;
    if (node >= n) return;
    const int g = lane >> 4;
    const int t = lane & 15;

    half8_t hv = *reinterpret_cast<const half8_t*>(Hn + (size_t)node * 128 + t * 8);
    half2_t h2[4];
#pragma unroll
    for (int j = 0; j < 4; j++) h2[j] = (half2_t){hv[2 * j], hv[2 * j + 1]};
    float es = exself[node];
    float esn = es * nrm[node];
    float acc[8];
    float denom;
    if (g == 0) {
#pragma unroll
        for (int j = 0; j < 8; j++) acc[j] = esn * (float)hv[j];
        denom = es;
    } else {
#pragma unroll
        for (int j = 0; j < 8; j++) acc[j] = 0.f;
        denom = 0.f;
    }

    const int p0 = rowst[node], p1 = rowst[node + 1];
    const int nit = (p1 - p0 + 7) >> 3;   // 8 edges per iteration (2 per group)

    bool vA0 = false, vB0 = false;
    half8_t av0, bv0;
    float nA0 = 0.f, nB0 = 0.f;
    if (nit > 0) {
        int pA = p0 + g, pB = pA + 4;
        vA0 = pA < p1; vB0 = pB < p1;
        int sA = vA0 ? csrc[pA] : node;
        int sB = vB0 ? csrc[pB] : node;
        av0 = *reinterpret_cast<const half8_t*>(Hn + (size_t)sA * 128 + t * 8);
        bv0 = *reinterpret_cast<const half8_t*>(Hn + (size_t)sB * 128 + t * 8);
        nA0 = nrm[sA]; nB0 = nrm[sB];
    }

    for (int k = 0; k < nit; k++) {
        bool vA1 = false, vB1 = false;
        half8_t av1, bv1;
        float nA1 = 0.f, nB1 = 0.f;
        if (k + 1 < nit) {
            int pA = p0 + (k + 1) * 8 + g, pB = pA + 4;
            vA1 = pA < p1; vB1 = pB < p1;
            int sA = vA1 ? csrc[pA] : node;
            int sB = vB1 ? csrc[pB] : node;
            av1 = *reinterpret_cast<const half8_t*>(Hn + (size_t)sA * 128 + t * 8);
            bv1 = *reinterpret_cast<const half8_t*>(Hn + (size_t)sB * 128 + t * 8);
            nA1 = nrm[sA]; nB1 = nrm[sB];
        }

        half2_t da2 = (half2_t){hv[0], hv[1]} * (half2_t){av0[0], av0[1]};
        half2_t db2 = (half2_t){hv[0], hv[1]} * (half2_t){bv0[0], bv0[1]};
#pragma unroll
        for (int j = 1; j < 4; j++) {
            da2 += h2[j] * (half2_t){av0[2 * j], av0[2 * j + 1]};
            db2 += h2[j] * (half2_t){bv0[2 * j], bv0[2 * j + 1]};
        }
        float dA = (float)da2[0] + (float)da2[1];
        float dB = (float)db2[0] + (float)db2[1];
#pragma unroll
        for (int m = 8; m > 0; m >>= 1) {
            dA += __shfl_xor(dA, m, 64);
            dB += __shfl_xor(dB, m, 64);
        }
        float exA = vA0 ? __expf(dA) : 0.f;
        float exB = vB0 ? __expf(dB) : 0.f;
        denom += exA + exB;
        float wA = exA * nA0, wB = exB * nB0;
#pragma unroll
        for (int j = 0; j < 8; j++) acc[j] += wA * (float)av0[j] + wB * (float)bv0[j];

        vA0 = vA1; vB0 = vB1; av0 = av1; bv0 = bv1; nA0 = nA1; nB0 = nB1;
    }

#pragma unroll
    for (int j = 0; j < 8; j++) {
        acc[j] += __shfl_xor(acc[j], 16, 64);
        acc[j] += __shfl_xor(acc[j], 32, 64);
    }
    denom += __shfl_xor(denom, 16, 64);
    denom += __shfl_xor(denom, 32, 64);

    if (g == 0) {
        float inv = 1.0f / denom;
        half8_t o;
#pragma unroll
        for (int j = 0; j < 8; j++)
            o[j] = (_Float16)fmaxf(acc[j] * inv, 0.f);   // fused ReLU + fp16
        *reinterpret_cast<half8_t*>(Oxf + (size_t)node * 128 + t * 8) = o;
    }
}

__global__ __launch_bounds__(256) void k_agg64_lsm(
    const _Float16* __restrict__ Hn, const float* __restrict__ nrm, const float* __restrict__ exself,
    const int* __restrict__ rowst, const int* __restrict__ csrc,
    float* __restrict__ OUT, int n)
{
    const int wave = threadIdx.x >> 6, lane = threadIdx.x & 63;
    const int node = blockIdx.x * 4 + wave;
    if (node >= n) return;
    const int g = lane >> 4;
    const int t = lane & 15;

    half4_t hv = *reinterpret_cast<const half4_t*>(Hn + (size_t)node * 64 + t * 4);
    half2_t h2[2] = {(half2_t){hv[0], hv[1]}, (half2_t){hv[2], hv[3]}};
    float es = exself[node];
    float esn = es * nrm[node];
    float acc[4];
    float denom;
    if (g == 0) {
#pragma unroll
        for (int j = 0; j < 4; j++) acc[j] = esn * (float)hv[j];
        denom = es;
    } else {
        acc[0] = acc[1] = acc[2] = acc[3] = 0.f;
        denom = 0.f;
    }

    const int p0 = rowst[node], p1 = rowst[node + 1];
    const int nit = (p1 - p0 + 7) >> 3;

    bool vA0 = false, vB0 = false;
    half4_t av0, bv0;
    float nA0 = 0.f, nB0 = 0.f;
    if (nit > 0) {
        int pA = p0 + g, pB = pA + 4;
        vA0 = pA < p1; vB0 = pB < p1;
        int sA = vA0 ? csrc[pA] : node;
        int sB = vB0 ? csrc[pB] : node;
        av0 = *reinterpret_cast<const half4_t*>(Hn + (size_t)sA * 64 + t * 4);
        bv0 = *reinterpret_cast<const half4_t*>(Hn + (size_t)sB * 64 + t * 4);
        nA0 = nrm[sA]; nB0 = nrm[sB];
    }

    for (int k = 0; k < nit; k++) {
        bool vA1 = false, vB1 = false;
        half4_t av1, bv1;
        float nA1 = 0.f, nB1 = 0.f;
        if (k + 1 < nit) {
            int pA = p0 + (k + 1) * 8 + g, pB = pA + 4;
            vA1 = pA < p1; vB1 = pB < p1;
            int sA = vA1 ? csrc[pA] : node;
            int sB = vB1 ? csrc[pB] : node;
            av1 = *reinterpret_cast<const half4_t*>(Hn + (size_t)sA * 64 + t * 4);
            bv1 = *reinterpret_cast<const half4_t*>(Hn + (size_t)sB * 64 + t * 4);
            nA1 = nrm[sA]; nB1 = nrm[sB];
        }

        half2_t da2 = h2[0] * (half2_t){av0[0], av0[1]};
        half2_t db2 = h2[0] * (half2_t){bv0[0], bv0[1]};
        da2 += h2[1] * (half2_t){av0[2], av0[3]};
        db2 += h2[1] * (half2_t){bv0[2], bv0[3]};
        float dA = (float)da2[0] + (float)da2[1];
        float dB = (float)db2[0] + (float)db2[1];
#pragma unroll
        for (int m = 8; m > 0; m >>= 1) {
            dA += __shfl_xor(dA, m, 64);
            dB += __shfl_xor(dB, m, 64);
        }
        float exA = vA0 ? __expf(dA) : 0.f;
        float exB = vB0 ? __expf(dB) : 0.f;
        denom += exA + exB;
        float wA = exA * nA0, wB = exB * nB0;
#pragma unroll
        for (int j = 0; j < 4; j++) acc[j] += wA * (float)av0[j] + wB * (float)bv0[j];

        vA0 = vA1; vB0 = vB1; av0 = av1; bv0 = bv1; nA0 = nA1; nB0 = nB1;
    }

#pragma unroll
    for (int j = 0; j < 4; j++) {
        acc[j] += __shfl_xor(acc[j], 16, 64);
        acc[j] += __shfl_xor(acc[j], 32, 64);
    }
    denom += __shfl_xor(denom, 16, 64);
    denom += __shfl_xor(denom, 32, 64);

    float inv = 1.0f / denom;
    float v0 = acc[0] * inv, v1 = acc[1] * inv, v2 = acc[2] * inv, v3 = acc[3] * inv;
    float mx = fmaxf(fmaxf(v0, v1), fmaxf(v2, v3));
#pragma unroll
    for (int m = 8; m > 0; m >>= 1) mx = fmaxf(mx, __shfl_xor(mx, m, 64));
    float se = __expf(v0 - mx) + __expf(v1 - mx) + __expf(v2 - mx) + __expf(v3 - mx);
#pragma unroll
    for (int m = 8; m > 0; m >>= 1) se += __shfl_xor(se, m, 64);
    float lse = mx + logf(se);
    if (g == 0) {
        float* op = OUT + (size_t)node * 64 + t * 4;
        *reinterpret_cast<float4*>(op) = make_float4(v0 - lse, v1 - lse, v2 - lse, v3 - lse);
    }
}

extern "C" void kernel_launch(void* const* d_in, const int* in_sizes, int n_in,
                              void* d_out, int out_size, void* d_ws, size_t ws_size,
                              hipStream_t stream)
{
    const float* x  = (const float*)d_in[0];
    const int*   ei = (const int*)d_in[1];
    const float* W1 = (const float*)d_in[2];
    const float* b1 = (const float*)d_in[3];
    const float* W2 = (const float*)d_in[4];
    const float* b2 = (const float*)d_in[5];
    const float* W3 = (const float*)d_in[6];
    const float* b3 = (const float*)d_in[7];
    float* out = (float*)d_out;

    const int n = in_sizes[0] / 128;
    const int e = in_sizes[1] / 2;
    const int* esrc = ei;
    const int* edst = ei + e;
    const int npad = (n + 15) & ~15;

    uintptr_t wp = ((uintptr_t)d_ws + 15) & ~(uintptr_t)15;
#define CARVE(ty, name, count) ty* name = (ty*)wp; wp = (wp + (size_t)(count) * sizeof(ty) + 15) & ~(uintptr_t)15
    CARVE(_Float16, xf, (size_t)npad * 128);
    CARVE(_Float16, hn16, (size_t)npad * 128);
    CARVE(float, nrm, n);
    CARVE(float, exs, n);
    CARVE(int, rowst, n + 1);
    CARVE(int, gh, 512);
    CARVE(int, binstart, 513);
    CARVE(int, bincur, 512);
    CARVE(unsigned, sorted, e);
    CARVE(int, csrc, e);
    CARVE(_Float16, w1h, 128 * 128);
    CARVE(_Float16, w1l, 128 * 128);
    CARVE(_Float16, w2h, 128 * 128);
    CARVE(_Float16, w2l, 128 * 128);
    CARVE(_Float16, w3h, 64 * 128);
    CARVE(_Float16, w3l, 64 * 128);
#undef CARVE

    const int nbin = (n + 127) >> 7;
    const int nchunk = (e + CSR_CHUNK - 1) / CSR_CHUNK;

    hipMemsetAsync(gh, 0, 512 * sizeof(int), stream);
    k_bh<<<nchunk, 256, 0, stream>>>(edst, gh, e, nbin);
    k_bscan<<<1, 512, 0, stream>>>(gh, binstart, bincur, rowst, e, nbin, n);
    k_scatter<<<nchunk, 256, 0, stream>>>(esrc, edst, bincur, sorted, e, nbin);
    k_fine<<<nbin, 256, 0, stream>>>(sorted, binstart, rowst, csrc, n);
    k_wsplit_all<<<160, 256, 0, stream>>>(W1, W2, W3, w1h, w1l, w2h, w2l, w3h, w3l);

    const int lgrid = 512;
    const int agrid = (n + 3) / 4;

    k_linear_mfma<128, true><<<lgrid, 256, 0, stream>>>(x, w1h, w1l, b1, hn16, nrm, exs, n);
    k_agg128<<<agrid, 256, 0, stream>>>(hn16, nrm, exs, rowst, csrc, xf, n);
    k_linear_mfma<128, false><<<lgrid, 256, 0, stream>>>(xf, w2h, w2l, b2, hn16, nrm, exs, n);
    k_agg128<<<agrid, 256, 0, stream>>>(hn16, nrm, exs, rowst, csrc, xf, n);
    k_linear_mfma<64, false><<<lgrid, 256, 0, stream>>>(xf, w3h, w3l, b3, hn16, nrm, exs, n);
    k_agg64_lsm<<<agrid, 256, 0, stream>>>(hn16, nrm, exs, rowst, csrc, out, n);
}